// Round 11
// baseline (132.662 us; speedup 1.0000x reference)
//
#include <hip/hip_runtime.h>

#define Bsz 16
#define Tsz 4096
#define Dsz 512
#define Ksz 256
#define Msz (Bsz * Tsz)      // 65536
#define CHUNK 64
#define NCH (Tsz / CHUNK)    // 64

typedef __attribute__((ext_vector_type(8))) short short8;
typedef __attribute__((ext_vector_type(4))) float f32x4;
typedef __attribute__((ext_vector_type(4))) unsigned int u32x4;

// ---------------- threefry2x32 (key = (0, 42)) — matches JAX exactly -------
__device__ __forceinline__ unsigned int rotl32(unsigned int x, int d) {
  return (x << d) | (x >> (32 - d));
}

__device__ void threefry_pair(unsigned int c0, unsigned int c1,
                              unsigned int& o0, unsigned int& o1) {
  const unsigned int k0 = 0u, k1 = 42u;
  const unsigned int k2 = k0 ^ k1 ^ 0x1BD11BDAu;
  unsigned int x0 = c0 + k0;
  unsigned int x1 = c1 + k1;
#define TF_ROUND(r) { x0 += x1; x1 = rotl32(x1, (r)); x1 ^= x0; }
  TF_ROUND(13) TF_ROUND(15) TF_ROUND(26) TF_ROUND(6)
  x0 += k1; x1 += k2 + 1u;
  TF_ROUND(17) TF_ROUND(29) TF_ROUND(16) TF_ROUND(24)
  x0 += k2; x1 += k0 + 2u;
  TF_ROUND(13) TF_ROUND(15) TF_ROUND(26) TF_ROUND(6)
  x0 += k0; x1 += k1 + 3u;
  TF_ROUND(17) TF_ROUND(29) TF_ROUND(16) TF_ROUND(24)
  x0 += k1; x1 += k2 + 4u;
  TF_ROUND(13) TF_ROUND(15) TF_ROUND(26) TF_ROUND(6)
  x0 += k2; x1 += k0 + 5u;
#undef TF_ROUND
  o0 = x0; o1 = x1;
}

// XLA ErfInv32 polynomial (math.cc)
__device__ float erfinv32(float x) {
  float w = -log1pf(-x * x);
  float p;
  if (w < 5.f) {
    w -= 2.5f;
    p = 2.81022636e-08f;
    p = fmaf(p, w, 3.43273939e-07f);
    p = fmaf(p, w, -3.5233877e-06f);
    p = fmaf(p, w, -4.39150654e-06f);
    p = fmaf(p, w, 0.00021858087f);
    p = fmaf(p, w, -0.00125372503f);
    p = fmaf(p, w, -0.00417768164f);
    p = fmaf(p, w, 0.246640727f);
    p = fmaf(p, w, 1.50140941f);
  } else {
    w = sqrtf(w) - 3.f;
    p = -0.000200214257f;
    p = fmaf(p, w, 0.000100950558f);
    p = fmaf(p, w, 0.00134934322f);
    p = fmaf(p, w, -0.00367342844f);
    p = fmaf(p, w, 0.00573950773f);
    p = fmaf(p, w, -0.0076224613f);
    p = fmaf(p, w, 0.00943887047f);
    p = fmaf(p, w, 1.00167406f);
    p = fmaf(p, w, 2.83297682f);
  }
  return p * x;
}

// JAX: bits -> uniform[-0.99999994, 1) -> sqrt(2)*erfinv
__device__ float bits_to_normal(unsigned int bits) {
  unsigned int fb = (bits >> 9) | 0x3f800000u;
  float f = __uint_as_float(fb) - 1.0f;   // [0,1)
  const float lo = -0.99999994f;          // nextafter(-1, 0) in f32
  float u = f * 2.0f + lo;                // hi - lo rounds to exactly 2.0f
  u = fmaxf(lo, u);
  return 1.41421356f * erfinv32(u);
}

__device__ float block_sum_512(float v, float* s_red) {
  #pragma unroll
  for (int o = 32; o > 0; o >>= 1) v += __shfl_down(v, o);
  const int lane = threadIdx.x & 63, wid = threadIdx.x >> 6;
  if (lane == 0) s_red[wid] = v;
  __syncthreads();
  float r = 0.f;
  #pragma unroll
  for (int i = 0; i < 8; ++i) r += s_red[i];
  __syncthreads();
  return r;
}

__device__ __forceinline__ unsigned int bf16rne(float f) {
  unsigned int u = __float_as_uint(f);
  return (u + 0x7FFFu + ((u >> 16) & 1u)) >> 16;
}

__device__ __forceinline__ void gld16(const float* g, float* l) {
  using gp = const __attribute__((address_space(1))) unsigned int*;
  using lp = __attribute__((address_space(3))) unsigned int*;
  __builtin_amdgcn_global_load_lds((gp)(const void*)g, (lp)(void*)l, 16, 0, 0);
}

// --------- prep1 (16 blocks x 512): partial_v[b][d] = sum_k W[k][d]*u0n[k] --
__global__ __launch_bounds__(512) void prep1_kernel(
    const float* __restrict__ W, float* __restrict__ partial_v) {
  __shared__ float s_u0[Ksz];
  __shared__ float s_red[8];
  const int tid = threadIdx.x;
  if (tid < 128) {
    unsigned int y0, y1;
    threefry_pair((unsigned int)tid, (unsigned int)(tid + 128), y0, y1);
    s_u0[tid] = bits_to_normal(y0);
    s_u0[tid + 128] = bits_to_normal(y1);
  }
  __syncthreads();
  float val = (tid < Ksz) ? s_u0[tid] * s_u0[tid] : 0.f;
  float ss = block_sum_512(val, s_red);
  float inv = 1.f / fmaxf(sqrtf(ss), 1e-7f);

  const int k0 = blockIdx.x * 16;
  float acc = 0.f;
  #pragma unroll
  for (int kk = 0; kk < 16; ++kk)
    acc = fmaf(W[(size_t)(k0 + kk) * Dsz + tid], s_u0[k0 + kk], acc);
  partial_v[blockIdx.x * Dsz + tid] = acc * inv;
}

// --------- prep2 (64 blocks x 512): v = normalize(sum partials); wv rows ---
__global__ __launch_bounds__(512) void prep2_kernel(
    const float* __restrict__ W, const float* __restrict__ partial_v,
    float* __restrict__ wv) {
  __shared__ float s_v[Dsz];
  __shared__ float s_red[8];
  __shared__ float s_p[8];
  const int tid = threadIdx.x;
  float acc = 0.f;
  #pragma unroll
  for (int b = 0; b < 16; ++b) acc += partial_v[b * Dsz + tid];
  float ssv = block_sum_512(acc * acc, s_red);
  float invv = 1.f / fmaxf(sqrtf(ssv), 1e-7f);
  s_v[tid] = acc * invv;
  __syncthreads();

  const int k = blockIdx.x * 4 + (tid >> 7);
  const int sub = tid & 127;
  const float* wr = W + (size_t)k * Dsz;
  float p = 0.f;
  #pragma unroll
  for (int j = sub; j < Dsz; j += 128) p = fmaf(wr[j], s_v[j], p);
  #pragma unroll
  for (int o = 32; o > 0; o >>= 1) p += __shfl_down(p, o);
  const int lane = tid & 63, wid = tid >> 6;
  if (lane == 0) s_p[wid] = p;
  __syncthreads();
  if (tid < 4) wv[blockIdx.x * 4 + tid] = s_p[2 * tid] + s_p[2 * tid + 1];
}

// --------- prep3 (1 block x 256): sigma + all per-k constants --------------
// consts layout (floats): [0]=ar [K]=ai [2K]=A64r [3K]=A64i [4K]=P4r [5K]=P4i
//   [6K]=P8r [7K]=P8i [8K]=P16r [9K]=P16i [10K]=P32r [11K]=P32i [12K]=inv_sigma
__global__ __launch_bounds__(256) void prep3_kernel(
    const float* __restrict__ s_real_raw, const float* __restrict__ s_imag,
    const float* __restrict__ tau_raw, const float* __restrict__ wv,
    float* __restrict__ consts) {
  __shared__ float s_p[4];
  const int tid = threadIdx.x;
  float v = wv[tid];
  float v2 = v * v;
  #pragma unroll
  for (int o = 32; o > 0; o >>= 1) v2 += __shfl_down(v2, o);
  const int lane = tid & 63, wid = tid >> 6;
  if (lane == 0) s_p[wid] = v2;
  __syncthreads();
  float sswv = s_p[0] + s_p[1] + s_p[2] + s_p[3];
  float sigma = sswv / fmaxf(sqrtf(sswv), 1e-7f);
  if (tid == 0) consts[12 * Ksz] = 1.f / sigma;

  float tr = tau_raw[0];
  float tau = fmaxf(tr, 0.f) + log1pf(expf(-fabsf(tr))) + 1e-3f;
  float srr = s_real_raw[tid];
  float sp = fmaxf(srr, 0.f) + log1pf(expf(-fabsf(srr)));
  float alpha0 = (sp + 1e-6f) * tau;
  float omega0 = s_imag[tid] * tau;
  const float dt = 1.f / 4095.f;
  float ad = alpha0 * dt, an = omega0 * dt;
  consts[tid]            = expf(-ad) * cosf(an);
  consts[Ksz + tid]      = expf(-ad) * sinf(an);
  consts[2 * Ksz + tid]  = expf(-ad * 64.f) * cosf(an * 64.f);
  consts[3 * Ksz + tid]  = expf(-ad * 64.f) * sinf(an * 64.f);
  consts[4 * Ksz + tid]  = expf(-ad * 4.f) * cosf(an * 4.f);
  consts[5 * Ksz + tid]  = expf(-ad * 4.f) * sinf(an * 4.f);
  consts[6 * Ksz + tid]  = expf(-ad * 8.f) * cosf(an * 8.f);
  consts[7 * Ksz + tid]  = expf(-ad * 8.f) * sinf(an * 8.f);
  consts[8 * Ksz + tid]  = expf(-ad * 16.f) * cosf(an * 16.f);
  consts[9 * Ksz + tid]  = expf(-ad * 16.f) * sinf(an * 16.f);
  consts[10 * Ksz + tid] = expf(-ad * 32.f) * cosf(an * 32.f);
  consts[11 * Ksz + tid] = expf(-ad * 32.f) * sinf(an * 32.f);
}

// --------- wpack: W/sigma -> bf16 h/l in MFMA B-fragment order -------------
__global__ __launch_bounds__(64) void wpack_kernel(
    const float* __restrict__ W, const float* __restrict__ consts,
    unsigned int* __restrict__ WfH, unsigned int* __restrict__ WfL) {
  const int kb = blockIdx.x >> 4;
  const int nb = blockIdx.x & 15;
  const int lane = threadIdx.x;
  const int lr = lane & 15, lg = lane >> 4;
  const float inv_sigma = consts[12 * Ksz];
  const float* src = W + (size_t)(nb * 16 + lr) * Dsz + kb * 32 + lg * 8;
  float v[8];
  *(float4*)&v[0] = *(const float4*)src;
  *(float4*)&v[4] = *(const float4*)(src + 4);
  unsigned int hh[4], ll[4];
  #pragma unroll
  for (int i = 0; i < 4; ++i) {
    float v0 = v[2 * i] * inv_sigma, v1 = v[2 * i + 1] * inv_sigma;
    unsigned int u0 = __float_as_uint(v0);
    unsigned int u1 = __float_as_uint(v1);
    hh[i] = (u0 >> 16) | (u1 & 0xFFFF0000u);
    float r0 = v0 - __uint_as_float(u0 & 0xFFFF0000u);
    float r1 = v1 - __uint_as_float(u1 & 0xFFFF0000u);
    ll[i] = bf16rne(r0) | (bf16rne(r1) << 16);
  }
  const size_t off = (size_t)blockIdx.x * 256 + lane * 4;   // in uints
  *(int4*)(WfH + off) = *(int4*)hh;
  *(int4*)(WfL + off) = *(int4*)ll;
}

// --------- MFMA GEMM + fused chunk-scan carry ------------------------------
// BM=128 (= 2 scan chunks), BN=256, BK=32. 512 thr = 8 waves (2m x 4n).
// m97-style staging: raw f32 A via global_load_lds into a 4-SLOT ring
// (4 x 16KB, ring-4 race-free vs k+2 prefetch), source XOR-swizzled so
// consume-side float4 ds_reads are conflict-light. ONE counted-vmcnt(2) +
// ONE s_barrier per K-tile; staging stays 1 tile in flight across barriers;
// no ds_writes, no lgkm drains. Consume-side f32->bf16 h/l split and per-acc
// hh->hl->lh MFMA order are bit-identical to rounds 4-10. LDS 64KB ->
// 2 blocks/CU (4 waves/SIMD). U stored bf16. Epilogue: round-10 carry.
__global__ __launch_bounds__(512, 2) void gemm_mfma(
    const float* __restrict__ X, const unsigned int* __restrict__ WfH,
    const unsigned int* __restrict__ WfL, const float* __restrict__ bias,
    const float* __restrict__ consts, unsigned short* __restrict__ U,
    float* __restrict__ carry) {
  __shared__ float ldsA[4][4096];   // 4 slots x 16KB (128 rows x 32 f32)

  const int tid = threadIdx.x;
  const size_t m0 = (size_t)blockIdx.x * 128;
  const int lane = tid & 63;
  const int wid = tid >> 6;             // 0..7
  const int wm = wid >> 2;              // 0..1 -> rows wm*64
  const int wn = wid & 3;               // 0..3 -> cols wn*64
  const int lr = lane & 15;
  const int lg = lane >> 4;

  // staging: thread t covers rows {srow, 64+srow}, 16B col-block (t&7),
  // holding global col-block (t&7) ^ (srow&7)  [source-swizzled layout]
  const int srow = tid >> 3;            // 0..63
  const int scol = ((tid & 7) ^ (srow & 7)) * 4;
  const float* gs0 = X + (m0 + srow) * Dsz + scol;
  const float* gs1 = X + (m0 + 64 + srow) * Dsz + scol;

  #define STAGE(kb) do {                                                     \
    float* lb = &ldsA[(kb) & 3][0] + wid * 256;   /* wave-uniform base */    \
    gld16(gs0 + (kb) * 32, lb);                                              \
    gld16(gs1 + (kb) * 32, lb + 2048);                                       \
  } while (0)

  const char* const wfhp = (const char*)WfH + (size_t)(wn * 4) * 1024 + lane * 16;
  const char* const wflp = (const char*)WfL + (size_t)(wn * 4) * 1024 + lane * 16;

  short8 bh[4], bl[4];
  #define LOADB(kb) do {                                                     \
    const size_t tb = (size_t)(kb) * 16384;                                  \
    _Pragma("unroll")                                                        \
    for (int q = 0; q < 4; ++q) {                                            \
      bh[q] = *(const short8*)(wfhp + tb + (size_t)q * 1024);                \
      bl[q] = *(const short8*)(wflp + tb + (size_t)q * 1024);                \
    }                                                                        \
  } while (0)

  f32x4 acc[4][4];
  #pragma unroll
  for (int i = 0; i < 4; ++i)
    #pragma unroll
    for (int j = 0; j < 4; ++j) acc[i][j] = (f32x4)(0.f);

  // one mf-pair: ds_read 2 fragments (raw f32, swizzled), convert, 24 MFMA
  #define PAIR(slotp, p) do {                                                \
    short8 ah[2], al[2];                                                     \
    _Pragma("unroll")                                                        \
    for (int m = 0; m < 2; ++m) {                                            \
      const int R = wm * 64 + (2 * (p) + m) * 16 + lr;                       \
      const float* rb = (slotp) + R * 32;                                    \
      float4 va = *(const float4*)(rb + ((lg * 2) ^ (lr & 7)) * 4);          \
      float4 vb = *(const float4*)(rb + ((lg * 2 + 1) ^ (lr & 7)) * 4);      \
      float v[8] = {va.x, va.y, va.z, va.w, vb.x, vb.y, vb.z, vb.w};         \
      unsigned int hh[4], llw[4];                                            \
      _Pragma("unroll")                                                      \
      for (int i = 0; i < 4; ++i) {                                          \
        float v0 = v[2 * i], v1 = v[2 * i + 1];                              \
        unsigned int u0 = __float_as_uint(v0);                               \
        unsigned int u1 = __float_as_uint(v1);                               \
        hh[i] = (u0 >> 16) | (u1 & 0xFFFF0000u);                             \
        float r0 = v0 - __uint_as_float(u0 & 0xFFFF0000u);                   \
        float r1 = v1 - __uint_as_float(u1 & 0xFFFF0000u);                   \
        llw[i] = bf16rne(r0) | (bf16rne(r1) << 16);                          \
      }                                                                      \
      u32x4 th = {hh[0], hh[1], hh[2], hh[3]};                               \
      u32x4 tl = {llw[0], llw[1], llw[2], llw[3]};                           \
      ah[m] = __builtin_bit_cast(short8, th);                                \
      al[m] = __builtin_bit_cast(short8, tl);                                \
    }                                                                        \
    _Pragma("unroll")                                                        \
    for (int m = 0; m < 2; ++m)                                              \
      _Pragma("unroll")                                                      \
      for (int nf = 0; nf < 4; ++nf)                                         \
        acc[2 * (p) + m][nf] = __builtin_amdgcn_mfma_f32_16x16x32_bf16(      \
            ah[m], bh[nf], acc[2 * (p) + m][nf], 0, 0, 0);                   \
    _Pragma("unroll")                                                        \
    for (int m = 0; m < 2; ++m)                                              \
      _Pragma("unroll")                                                      \
      for (int nf = 0; nf < 4; ++nf)                                         \
        acc[2 * (p) + m][nf] = __builtin_amdgcn_mfma_f32_16x16x32_bf16(      \
            ah[m], bl[nf], acc[2 * (p) + m][nf], 0, 0, 0);                   \
    _Pragma("unroll")                                                        \
    for (int m = 0; m < 2; ++m)                                              \
      _Pragma("unroll")                                                      \
      for (int nf = 0; nf < 4; ++nf)                                         \
        acc[2 * (p) + m][nf] = __builtin_amdgcn_mfma_f32_16x16x32_bf16(      \
            al[m], bh[nf], acc[2 * (p) + m][nf], 0, 0, 0);                   \
  } while (0)

  // prologue: 2 tiles in flight
  STAGE(0);
  STAGE(1);

  for (int k = 0; k < 14; ++k) {
    LOADB(k);
    __builtin_amdgcn_sched_barrier(0);          // keep B older than stage
    STAGE(k + 2);
    asm volatile("s_waitcnt vmcnt(2)" ::: "memory");  // B(k)+stage(k,k+1) done
    __builtin_amdgcn_s_barrier();
    __builtin_amdgcn_sched_barrier(0);
    const float* slotp = &ldsA[k & 3][0];
    PAIR(slotp, 0);
    PAIR(slotp, 1);
  }
  #pragma unroll
  for (int k = 14; k < 16; ++k) {
    LOADB(k);
    asm volatile("s_waitcnt vmcnt(0)" ::: "memory");
    __builtin_amdgcn_s_barrier();
    __builtin_amdgcn_sched_barrier(0);
    const float* slotp = &ldsA[k & 3][0];
    PAIR(slotp, 0);
    PAIR(slotp, 1);
  }
  #undef PAIR
  #undef LOADB
  #undef STAGE

  // ---- epilogue: bf16 U store + fused 64-row chunk carry ----
  // wave's rows = one chunk (index 2*blockIdx+wm): t = mf*16 + lg*4 + j,
  // weight a^{63-t} = P4^{3-lg} * P16^{3-mf} * a^{3-j}
  #pragma unroll
  for (int nf = 0; nf < 4; ++nf) {
    const int n = wn * 64 + nf * 16 + lr;
    const float bv = bias[n];
    const float ar_ = consts[n],           ai_ = consts[Ksz + n];
    const float p4r = consts[4 * Ksz + n], p4i = consts[5 * Ksz + n];
    const float p8r = consts[6 * Ksz + n], p8i = consts[7 * Ksz + n];
    const float p16r = consts[8 * Ksz + n], p16i = consts[9 * Ksz + n];
    const int e = 3 - lg;
    const float b1r = (e & 1) ? p4r : 1.f, b1i = (e & 1) ? p4i : 0.f;
    const float b2r = (e & 2) ? p8r : 1.f, b2i = (e & 2) ? p8i : 0.f;
    float wr = b1r * b2r - b1i * b2i;
    float wi = b1r * b2i + b1i * b2r;
    float Sr = 0.f, Si = 0.f;
    #pragma unroll
    for (int mf = 3; mf >= 0; --mf) {
      float vr = wr, vi = wi;
      #pragma unroll
      for (int j = 3; j >= 0; --j) {
        const float u = acc[mf][nf][j] + bv;
        U[(m0 + wm * 64 + mf * 16 + lg * 4 + j) * Ksz + n] =
            (unsigned short)bf16rne(u);
        Sr = fmaf(u, vr, Sr);
        Si = fmaf(u, vi, Si);
        if (j) {
          float t_ = vr * ar_ - vi * ai_;
          vi = vr * ai_ + vi * ar_;
          vr = t_;
        }
      }
      if (mf) {
        float t_ = wr * p16r - wi * p16i;
        wi = wr * p16i + wi * p16r;
        wr = t_;
      }
    }
    Sr += __shfl_xor(Sr, 16); Si += __shfl_xor(Si, 16);
    Sr += __shfl_xor(Sr, 32); Si += __shfl_xor(Si, 32);
    if (lg == 0)
      ((float2*)carry)[(size_t)(blockIdx.x * 2 + wm) * Ksz + n] =
          make_float2(Sr, Si);
  }
}

// --------- scan pass 2: exclusive prefix over chunks (A = a^64) ------------
__global__ __launch_bounds__(64) void scan_prefix(
    const float* __restrict__ consts, const float* __restrict__ carry,
    float* __restrict__ prefix) {
  const int k = blockIdx.y * 64 + threadIdx.x;
  const int b = blockIdx.x;
  const float Ar = consts[2 * Ksz + k], Ai = consts[3 * Ksz + k];
  const float2* cp = (const float2*)carry;
  float2* pp = (float2*)prefix;
  float c = 0.f, s = 0.f;
  for (int m = 0; m < NCH; ++m) {
    const size_t idx = (size_t)(b * NCH + m) * Ksz + k;
    pp[idx] = make_float2(c, s);
    float2 L = cp[idx];
    float cn = fmaf(Ar, c, fmaf(-Ai, s, L.x));
    float sn = fmaf(Ai, c, fmaf(Ar, s, L.y));
    c = cn; s = sn;
  }
}

// --------- scan pass 3: rescan chunk from true carry, write output ---------
__global__ __launch_bounds__(256) void scan_final(
    const unsigned short* __restrict__ U, const float* __restrict__ consts,
    const float* __restrict__ prefix, float* __restrict__ out) {
  const int k = threadIdx.x;
  const int bm = blockIdx.x;
  const float ar = consts[k], ai = consts[Ksz + k];
  float2 w = ((const float2*)prefix)[(size_t)bm * Ksz + k];
  float c = w.x, s = w.y;
  const unsigned short* up = U + (size_t)bm * (CHUNK * Ksz) + k;
  float* op = out + (size_t)bm * (CHUNK * 2 * Ksz);
  #pragma unroll 4
  for (int t = 0; t < CHUNK; ++t) {
    float u = __uint_as_float((unsigned int)up[(size_t)t * Ksz] << 16);
    float cn = fmaf(ar, c, fmaf(-ai, s, u));
    s = fmaf(ai, c, ar * s);
    c = cn;
    op[(size_t)t * 2 * Ksz + k] = c;
    op[(size_t)t * 2 * Ksz + Ksz + k] = s;
  }
}

extern "C" void kernel_launch(void* const* d_in, const int* in_sizes, int n_in,
                              void* d_out, int out_size, void* d_ws, size_t ws_size,
                              hipStream_t stream) {
  const float* x    = (const float*)d_in[0];
  const float* srr  = (const float*)d_in[1];
  const float* sim  = (const float*)d_in[2];
  const float* traw = (const float*)d_in[3];
  const float* W    = (const float*)d_in[4];
  const float* bias = (const float*)d_in[5];
  float* out = (float*)d_out;

  // ws layout (floats): consts[4096] | U(bf16: Msz*Ksz ushorts = 8388608 fl)
  //   | carry[524288] | prefix[524288] | WfH[65536] | WfL[65536]
  //   | partial_v[8192] | wv[256]
  float* wsf    = (float*)d_ws;
  float* consts = wsf;
  unsigned short* U = (unsigned short*)(wsf + 4096);
  float* carry  = wsf + 4096 + 8388608;
  float* prefix = carry + (size_t)2 * Bsz * NCH * Ksz;
  unsigned int* WfH = (unsigned int*)(prefix + (size_t)2 * Bsz * NCH * Ksz);
  unsigned int* WfL = WfH + 65536;
  float* partial_v  = (float*)(WfL + 65536);
  float* wv         = partial_v + 16 * Dsz;

  prep1_kernel<<<16, 512, 0, stream>>>(W, partial_v);
  prep2_kernel<<<64, 512, 0, stream>>>(W, partial_v, wv);
  prep3_kernel<<<1, 256, 0, stream>>>(srr, sim, traw, wv, consts);
  wpack_kernel<<<256, 64, 0, stream>>>(W, consts, WfH, WfL);
  gemm_mfma<<<Msz / 128, 512, 0, stream>>>(x, WfH, WfL, bias, consts, U, carry);
  scan_prefix<<<dim3(Bsz, Ksz / 64), 64, 0, stream>>>(consts, carry, prefix);
  scan_final<<<Bsz * NCH, Ksz, 0, stream>>>(U, consts, prefix, out);
}

// Round 12
// 128.751 us; speedup vs baseline: 1.0304x; 1.0304x over previous
//
#include <hip/hip_runtime.h>

#define Bsz 16
#define Tsz 4096
#define Dsz 512
#define Ksz 256
#define Msz (Bsz * Tsz)      // 65536
#define CHUNK 64
#define NCH (Tsz / CHUNK)    // 64

typedef __attribute__((ext_vector_type(8))) short short8;
typedef __attribute__((ext_vector_type(4))) float f32x4;
typedef __attribute__((ext_vector_type(4))) unsigned int u32x4;

// ---------------- threefry2x32 (key = (0, 42)) — matches JAX exactly -------
__device__ __forceinline__ unsigned int rotl32(unsigned int x, int d) {
  return (x << d) | (x >> (32 - d));
}

__device__ void threefry_pair(unsigned int c0, unsigned int c1,
                              unsigned int& o0, unsigned int& o1) {
  const unsigned int k0 = 0u, k1 = 42u;
  const unsigned int k2 = k0 ^ k1 ^ 0x1BD11BDAu;
  unsigned int x0 = c0 + k0;
  unsigned int x1 = c1 + k1;
#define TF_ROUND(r) { x0 += x1; x1 = rotl32(x1, (r)); x1 ^= x0; }
  TF_ROUND(13) TF_ROUND(15) TF_ROUND(26) TF_ROUND(6)
  x0 += k1; x1 += k2 + 1u;
  TF_ROUND(17) TF_ROUND(29) TF_ROUND(16) TF_ROUND(24)
  x0 += k2; x1 += k0 + 2u;
  TF_ROUND(13) TF_ROUND(15) TF_ROUND(26) TF_ROUND(6)
  x0 += k0; x1 += k1 + 3u;
  TF_ROUND(17) TF_ROUND(29) TF_ROUND(16) TF_ROUND(24)
  x0 += k1; x1 += k2 + 4u;
  TF_ROUND(13) TF_ROUND(15) TF_ROUND(26) TF_ROUND(6)
  x0 += k2; x1 += k0 + 5u;
#undef TF_ROUND
  o0 = x0; o1 = x1;
}

// XLA ErfInv32 polynomial (math.cc)
__device__ float erfinv32(float x) {
  float w = -log1pf(-x * x);
  float p;
  if (w < 5.f) {
    w -= 2.5f;
    p = 2.81022636e-08f;
    p = fmaf(p, w, 3.43273939e-07f);
    p = fmaf(p, w, -3.5233877e-06f);
    p = fmaf(p, w, -4.39150654e-06f);
    p = fmaf(p, w, 0.00021858087f);
    p = fmaf(p, w, -0.00125372503f);
    p = fmaf(p, w, -0.00417768164f);
    p = fmaf(p, w, 0.246640727f);
    p = fmaf(p, w, 1.50140941f);
  } else {
    w = sqrtf(w) - 3.f;
    p = -0.000200214257f;
    p = fmaf(p, w, 0.000100950558f);
    p = fmaf(p, w, 0.00134934322f);
    p = fmaf(p, w, -0.00367342844f);
    p = fmaf(p, w, 0.00573950773f);
    p = fmaf(p, w, -0.0076224613f);
    p = fmaf(p, w, 0.00943887047f);
    p = fmaf(p, w, 1.00167406f);
    p = fmaf(p, w, 2.83297682f);
  }
  return p * x;
}

// JAX: bits -> uniform[-0.99999994, 1) -> sqrt(2)*erfinv
__device__ float bits_to_normal(unsigned int bits) {
  unsigned int fb = (bits >> 9) | 0x3f800000u;
  float f = __uint_as_float(fb) - 1.0f;   // [0,1)
  const float lo = -0.99999994f;          // nextafter(-1, 0) in f32
  float u = f * 2.0f + lo;                // hi - lo rounds to exactly 2.0f
  u = fmaxf(lo, u);
  return 1.41421356f * erfinv32(u);
}

__device__ float block_sum_512(float v, float* s_red) {
  #pragma unroll
  for (int o = 32; o > 0; o >>= 1) v += __shfl_down(v, o);
  const int lane = threadIdx.x & 63, wid = threadIdx.x >> 6;
  if (lane == 0) s_red[wid] = v;
  __syncthreads();
  float r = 0.f;
  #pragma unroll
  for (int i = 0; i < 8; ++i) r += s_red[i];
  __syncthreads();
  return r;
}

__device__ __forceinline__ unsigned int bf16rne(float f) {
  unsigned int u = __float_as_uint(f);
  return (u + 0x7FFFu + ((u >> 16) & 1u)) >> 16;
}

__device__ __forceinline__ void gld16(const float* g, float* l) {
  using gp = const __attribute__((address_space(1))) unsigned int*;
  using lp = __attribute__((address_space(3))) unsigned int*;
  __builtin_amdgcn_global_load_lds((gp)(const void*)g, (lp)(void*)l, 16, 0, 0);
}

// --------- prep1 (16 blocks x 512): partial_v[b][d] = sum_k W[k][d]*u0n[k] --
__global__ __launch_bounds__(512) void prep1_kernel(
    const float* __restrict__ W, float* __restrict__ partial_v) {
  __shared__ float s_u0[Ksz];
  __shared__ float s_red[8];
  const int tid = threadIdx.x;
  if (tid < 128) {
    unsigned int y0, y1;
    threefry_pair((unsigned int)tid, (unsigned int)(tid + 128), y0, y1);
    s_u0[tid] = bits_to_normal(y0);
    s_u0[tid + 128] = bits_to_normal(y1);
  }
  __syncthreads();
  float val = (tid < Ksz) ? s_u0[tid] * s_u0[tid] : 0.f;
  float ss = block_sum_512(val, s_red);
  float inv = 1.f / fmaxf(sqrtf(ss), 1e-7f);

  const int k0 = blockIdx.x * 16;
  float acc = 0.f;
  #pragma unroll
  for (int kk = 0; kk < 16; ++kk)
    acc = fmaf(W[(size_t)(k0 + kk) * Dsz + tid], s_u0[k0 + kk], acc);
  partial_v[blockIdx.x * Dsz + tid] = acc * inv;
}

// --------- prep2 (64 blocks x 512): v = normalize(sum partials); wv rows ---
__global__ __launch_bounds__(512) void prep2_kernel(
    const float* __restrict__ W, const float* __restrict__ partial_v,
    float* __restrict__ wv) {
  __shared__ float s_v[Dsz];
  __shared__ float s_red[8];
  __shared__ float s_p[8];
  const int tid = threadIdx.x;
  float acc = 0.f;
  #pragma unroll
  for (int b = 0; b < 16; ++b) acc += partial_v[b * Dsz + tid];
  float ssv = block_sum_512(acc * acc, s_red);
  float invv = 1.f / fmaxf(sqrtf(ssv), 1e-7f);
  s_v[tid] = acc * invv;
  __syncthreads();

  const int k = blockIdx.x * 4 + (tid >> 7);
  const int sub = tid & 127;
  const float* wr = W + (size_t)k * Dsz;
  float p = 0.f;
  #pragma unroll
  for (int j = sub; j < Dsz; j += 128) p = fmaf(wr[j], s_v[j], p);
  #pragma unroll
  for (int o = 32; o > 0; o >>= 1) p += __shfl_down(p, o);
  const int lane = tid & 63, wid = tid >> 6;
  if (lane == 0) s_p[wid] = p;
  __syncthreads();
  if (tid < 4) wv[blockIdx.x * 4 + tid] = s_p[2 * tid] + s_p[2 * tid + 1];
}

// --------- prep3 (1 block x 256): sigma + all per-k constants --------------
// consts layout (floats): [0]=ar [K]=ai [2K]=A64r [3K]=A64i [4K]=P4r [5K]=P4i
//   [6K]=P8r [7K]=P8i [8K]=P16r [9K]=P16i [10K]=P32r [11K]=P32i [12K]=inv_sigma
__global__ __launch_bounds__(256) void prep3_kernel(
    const float* __restrict__ s_real_raw, const float* __restrict__ s_imag,
    const float* __restrict__ tau_raw, const float* __restrict__ wv,
    float* __restrict__ consts) {
  __shared__ float s_p[4];
  const int tid = threadIdx.x;
  float v = wv[tid];
  float v2 = v * v;
  #pragma unroll
  for (int o = 32; o > 0; o >>= 1) v2 += __shfl_down(v2, o);
  const int lane = tid & 63, wid = tid >> 6;
  if (lane == 0) s_p[wid] = v2;
  __syncthreads();
  float sswv = s_p[0] + s_p[1] + s_p[2] + s_p[3];
  float sigma = sswv / fmaxf(sqrtf(sswv), 1e-7f);
  if (tid == 0) consts[12 * Ksz] = 1.f / sigma;

  float tr = tau_raw[0];
  float tau = fmaxf(tr, 0.f) + log1pf(expf(-fabsf(tr))) + 1e-3f;
  float srr = s_real_raw[tid];
  float sp = fmaxf(srr, 0.f) + log1pf(expf(-fabsf(srr)));
  float alpha0 = (sp + 1e-6f) * tau;
  float omega0 = s_imag[tid] * tau;
  const float dt = 1.f / 4095.f;
  float ad = alpha0 * dt, an = omega0 * dt;
  consts[tid]            = expf(-ad) * cosf(an);
  consts[Ksz + tid]      = expf(-ad) * sinf(an);
  consts[2 * Ksz + tid]  = expf(-ad * 64.f) * cosf(an * 64.f);
  consts[3 * Ksz + tid]  = expf(-ad * 64.f) * sinf(an * 64.f);
  consts[4 * Ksz + tid]  = expf(-ad * 4.f) * cosf(an * 4.f);
  consts[5 * Ksz + tid]  = expf(-ad * 4.f) * sinf(an * 4.f);
  consts[6 * Ksz + tid]  = expf(-ad * 8.f) * cosf(an * 8.f);
  consts[7 * Ksz + tid]  = expf(-ad * 8.f) * sinf(an * 8.f);
  consts[8 * Ksz + tid]  = expf(-ad * 16.f) * cosf(an * 16.f);
  consts[9 * Ksz + tid]  = expf(-ad * 16.f) * sinf(an * 16.f);
  consts[10 * Ksz + tid] = expf(-ad * 32.f) * cosf(an * 32.f);
  consts[11 * Ksz + tid] = expf(-ad * 32.f) * sinf(an * 32.f);
}

// --------- wpack: W/sigma -> bf16 h/l in MFMA B-fragment order -------------
__global__ __launch_bounds__(64) void wpack_kernel(
    const float* __restrict__ W, const float* __restrict__ consts,
    unsigned int* __restrict__ WfH, unsigned int* __restrict__ WfL) {
  const int kb = blockIdx.x >> 4;
  const int nb = blockIdx.x & 15;
  const int lane = threadIdx.x;
  const int lr = lane & 15, lg = lane >> 4;
  const float inv_sigma = consts[12 * Ksz];
  const float* src = W + (size_t)(nb * 16 + lr) * Dsz + kb * 32 + lg * 8;
  float v[8];
  *(float4*)&v[0] = *(const float4*)src;
  *(float4*)&v[4] = *(const float4*)(src + 4);
  unsigned int hh[4], ll[4];
  #pragma unroll
  for (int i = 0; i < 4; ++i) {
    float v0 = v[2 * i] * inv_sigma, v1 = v[2 * i + 1] * inv_sigma;
    unsigned int u0 = __float_as_uint(v0);
    unsigned int u1 = __float_as_uint(v1);
    hh[i] = (u0 >> 16) | (u1 & 0xFFFF0000u);
    float r0 = v0 - __uint_as_float(u0 & 0xFFFF0000u);
    float r1 = v1 - __uint_as_float(u1 & 0xFFFF0000u);
    ll[i] = bf16rne(r0) | (bf16rne(r1) << 16);
  }
  const size_t off = (size_t)blockIdx.x * 256 + lane * 4;   // in uints
  *(int4*)(WfH + off) = *(int4*)hh;
  *(int4*)(WfL + off) = *(int4*)ll;
}

// --------- MFMA GEMM + fused chunk-scan carry ------------------------------
// BM=64 (= one scan chunk), BN=256, BK=32. 256 thr = 4 waves (wn 0..3).
// ZERO-BARRIER design: each wave stages ITS OWN copy of the 64 A-rows into a
// PRIVATE 2-slot LDS ring via global_load_lds (redundant 4x across waves, but
// L2-absorbed) and syncs only on its own counted vmcnt. No s_barrier, no
// lgkm drains, no cross-wave races (slots private). Per-tile ledger:
//   issue LOADB(k+1) [8] ; STAGE(k+1) [8] ; vmcnt(16) -> stage(k)+B(k) done.
// Consume-side f32->bf16 h/l split + per-acc hh->hl->lh order: U bit-identical
// to all prior rounds. U stored bf16. Epilogue = round-5 proven carry.
__global__ __launch_bounds__(256, 2) void gemm_mfma(
    const float* __restrict__ X, const unsigned int* __restrict__ WfH,
    const unsigned int* __restrict__ WfL, const float* __restrict__ bias,
    const float* __restrict__ consts, unsigned short* __restrict__ U,
    float* __restrict__ carry) {
  __shared__ float lds[4][2][2048];   // [wave][slot] 8KB = 64 rows x 32 f32

  const int tid = threadIdx.x;
  const size_t m0 = (size_t)blockIdx.x * 64;
  const int lane = tid & 63;
  const int wn = tid >> 6;              // 0..3, wave = 64 rows x 64 cols
  const int lr = lane & 15;
  const int lg = lane >> 4;

  // per-lane staging source: issue i covers rows 8i..8i+7; lane -> row
  // 8i + (lane>>3), LDS colblock (lane&7) holding source colblock
  // (lane&7)^(row&7)  [XOR source-swizzle; row&7 == (lane>>3)&7]
  const int srow = lane >> 3;
  const int scb = (lane & 7) ^ (srow & 7);
  const float* gsA = X + (m0 + srow) * Dsz + scb * 4;

  #define STAGE(kb) do {                                                     \
    float* lb = &lds[wn][(kb) & 1][0];                                       \
    _Pragma("unroll")                                                        \
    for (int i = 0; i < 8; ++i)                                              \
      gld16(gsA + (size_t)(8 * i) * Dsz + (kb) * 32, lb + i * 256);          \
  } while (0)

  const char* const wfhp = (const char*)WfH + (size_t)wn * 4096 + lane * 16;
  const char* const wflp = (const char*)WfL + (size_t)wn * 4096 + lane * 16;

  short8 bhA[4], blA[4], bhB[4], blB[4];
  #define LOADB(bh_, bl_, kb) do {                                           \
    const size_t tb = (size_t)(kb) * 16384;                                  \
    _Pragma("unroll")                                                        \
    for (int q = 0; q < 4; ++q) {                                            \
      bh_[q] = *(const short8*)(wfhp + tb + (size_t)q * 1024);               \
      bl_[q] = *(const short8*)(wflp + tb + (size_t)q * 1024);               \
    }                                                                        \
  } while (0)

  f32x4 acc[4][4];
  #pragma unroll
  for (int i = 0; i < 4; ++i)
    #pragma unroll
    for (int j = 0; j < 4; ++j) acc[i][j] = (f32x4)(0.f);

  // 2 mf-rows: ds_read raw f32 (swizzled), convert (bit-identical split),
  // 24 MFMA in hh->hl->lh per-acc order
  #define PAIR(slotp, p, bh_, bl_) do {                                      \
    short8 ah[2], al[2];                                                     \
    _Pragma("unroll")                                                        \
    for (int m = 0; m < 2; ++m) {                                            \
      const int R = (2 * (p) + m) * 16 + lr;                                 \
      const float* rb = (slotp) + R * 32;                                    \
      float4 va = *(const float4*)(rb + ((lg * 2) ^ (lr & 7)) * 4);          \
      float4 vb = *(const float4*)(rb + ((lg * 2 + 1) ^ (lr & 7)) * 4);      \
      float v[8] = {va.x, va.y, va.z, va.w, vb.x, vb.y, vb.z, vb.w};         \
      unsigned int hh[4], llw[4];                                            \
      _Pragma("unroll")                                                      \
      for (int i = 0; i < 4; ++i) {                                          \
        float v0 = v[2 * i], v1 = v[2 * i + 1];                              \
        unsigned int u0 = __float_as_uint(v0);                               \
        unsigned int u1 = __float_as_uint(v1);                               \
        hh[i] = (u0 >> 16) | (u1 & 0xFFFF0000u);                             \
        float r0 = v0 - __uint_as_float(u0 & 0xFFFF0000u);                   \
        float r1 = v1 - __uint_as_float(u1 & 0xFFFF0000u);                   \
        llw[i] = bf16rne(r0) | (bf16rne(r1) << 16);                          \
      }                                                                      \
      u32x4 th = {hh[0], hh[1], hh[2], hh[3]};                               \
      u32x4 tl = {llw[0], llw[1], llw[2], llw[3]};                           \
      ah[m] = __builtin_bit_cast(short8, th);                                \
      al[m] = __builtin_bit_cast(short8, tl);                                \
    }                                                                        \
    _Pragma("unroll")                                                        \
    for (int m = 0; m < 2; ++m)                                              \
      _Pragma("unroll")                                                      \
      for (int nf = 0; nf < 4; ++nf)                                         \
        acc[2 * (p) + m][nf] = __builtin_amdgcn_mfma_f32_16x16x32_bf16(      \
            ah[m], bh_[nf], acc[2 * (p) + m][nf], 0, 0, 0);                  \
    _Pragma("unroll")                                                        \
    for (int m = 0; m < 2; ++m)                                              \
      _Pragma("unroll")                                                      \
      for (int nf = 0; nf < 4; ++nf)                                         \
        acc[2 * (p) + m][nf] = __builtin_amdgcn_mfma_f32_16x16x32_bf16(      \
            ah[m], bl_[nf], acc[2 * (p) + m][nf], 0, 0, 0);                  \
    _Pragma("unroll")                                                        \
    for (int m = 0; m < 2; ++m)                                              \
      _Pragma("unroll")                                                      \
      for (int nf = 0; nf < 4; ++nf)                                         \
        acc[2 * (p) + m][nf] = __builtin_amdgcn_mfma_f32_16x16x32_bf16(      \
            al[m], bh_[nf], acc[2 * (p) + m][nf], 0, 0, 0);                  \
  } while (0)

  #define SB() __builtin_amdgcn_sched_barrier(0)

  // TILE k: consume B-cur + slot(k&1); prefetch B(k+1)->B-next, stage(k+1).
  #define TILE(k, bCh, bCl, bNh, bNl) do {                                   \
    if ((k) + 1 < 16) {                                                      \
      LOADB(bNh, bNl, (k) + 1); SB();                                        \
      STAGE((k) + 1); SB();                                                  \
      asm volatile("s_waitcnt vmcnt(16)" ::: "memory");                      \
    } else {                                                                 \
      asm volatile("s_waitcnt vmcnt(0)" ::: "memory");                       \
    }                                                                        \
    SB();                                                                    \
    const float* slotp = &lds[wn][(k) & 1][0];                               \
    PAIR(slotp, 0, bCh, bCl);                                                \
    PAIR(slotp, 1, bCh, bCl);                                                \
  } while (0)

  // prologue: B(0) then stage(0)  [B older -> vmcnt(16) at k=0 drains both]
  LOADB(bhA, blA, 0); SB();
  STAGE(0); SB();

  for (int k = 0; k < 16; k += 2) {
    TILE(k,     bhA, blA, bhB, blB);
    TILE(k + 1, bhB, blB, bhA, blA);
  }
  #undef TILE
  #undef SB
  #undef PAIR
  #undef LOADB
  #undef STAGE

  // ---- epilogue: bf16 U store + fused 64-row chunk carry (round-5 form) ----
  // t = mf*16 + lg*4 + j; weight a^{63-t} = P4^{3-lg} * P16^{3-mf} * a^{3-j}
  #pragma unroll
  for (int nf = 0; nf < 4; ++nf) {
    const int n = wn * 64 + nf * 16 + lr;
    const float bv = bias[n];
    const float ar_ = consts[n],           ai_ = consts[Ksz + n];
    const float p4r = consts[4 * Ksz + n], p4i = consts[5 * Ksz + n];
    const float p8r = consts[6 * Ksz + n], p8i = consts[7 * Ksz + n];
    const float p16r = consts[8 * Ksz + n], p16i = consts[9 * Ksz + n];
    const int e = 3 - lg;
    const float b1r = (e & 1) ? p4r : 1.f, b1i = (e & 1) ? p4i : 0.f;
    const float b2r = (e & 2) ? p8r : 1.f, b2i = (e & 2) ? p8i : 0.f;
    float wr = b1r * b2r - b1i * b2i;
    float wi = b1r * b2i + b1i * b2r;
    float Sr = 0.f, Si = 0.f;
    #pragma unroll
    for (int mf = 3; mf >= 0; --mf) {
      float vr = wr, vi = wi;
      #pragma unroll
      for (int j = 3; j >= 0; --j) {
        const float u = acc[mf][nf][j] + bv;
        U[(m0 + mf * 16 + lg * 4 + j) * Ksz + n] = (unsigned short)bf16rne(u);
        Sr = fmaf(u, vr, Sr);
        Si = fmaf(u, vi, Si);
        if (j) {
          float t_ = vr * ar_ - vi * ai_;
          vi = vr * ai_ + vi * ar_;
          vr = t_;
        }
      }
      if (mf) {
        float t_ = wr * p16r - wi * p16i;
        wi = wr * p16i + wi * p16r;
        wr = t_;
      }
    }
    Sr += __shfl_xor(Sr, 16); Si += __shfl_xor(Si, 16);
    Sr += __shfl_xor(Sr, 32); Si += __shfl_xor(Si, 32);
    if (lg == 0)
      ((float2*)carry)[(size_t)blockIdx.x * Ksz + n] = make_float2(Sr, Si);
  }
}

// --------- scan pass 2: exclusive prefix over chunks (A = a^64) ------------
__global__ __launch_bounds__(64) void scan_prefix(
    const float* __restrict__ consts, const float* __restrict__ carry,
    float* __restrict__ prefix) {
  const int k = blockIdx.y * 64 + threadIdx.x;
  const int b = blockIdx.x;
  const float Ar = consts[2 * Ksz + k], Ai = consts[3 * Ksz + k];
  const float2* cp = (const float2*)carry;
  float2* pp = (float2*)prefix;
  float c = 0.f, s = 0.f;
  for (int m = 0; m < NCH; ++m) {
    const size_t idx = (size_t)(b * NCH + m) * Ksz + k;
    pp[idx] = make_float2(c, s);
    float2 L = cp[idx];
    float cn = fmaf(Ar, c, fmaf(-Ai, s, L.x));
    float sn = fmaf(Ai, c, fmaf(Ar, s, L.y));
    c = cn; s = sn;
  }
}

// --------- scan pass 3: rescan chunk from true carry, write output ---------
__global__ __launch_bounds__(256) void scan_final(
    const unsigned short* __restrict__ U, const float* __restrict__ consts,
    const float* __restrict__ prefix, float* __restrict__ out) {
  const int k = threadIdx.x;
  const int bm = blockIdx.x;
  const float ar = consts[k], ai = consts[Ksz + k];
  float2 w = ((const float2*)prefix)[(size_t)bm * Ksz + k];
  float c = w.x, s = w.y;
  const unsigned short* up = U + (size_t)bm * (CHUNK * Ksz) + k;
  float* op = out + (size_t)bm * (CHUNK * 2 * Ksz);
  #pragma unroll 4
  for (int t = 0; t < CHUNK; ++t) {
    float u = __uint_as_float((unsigned int)up[(size_t)t * Ksz] << 16);
    float cn = fmaf(ar, c, fmaf(-ai, s, u));
    s = fmaf(ai, c, ar * s);
    c = cn;
    op[(size_t)t * 2 * Ksz + k] = c;
    op[(size_t)t * 2 * Ksz + Ksz + k] = s;
  }
}

extern "C" void kernel_launch(void* const* d_in, const int* in_sizes, int n_in,
                              void* d_out, int out_size, void* d_ws, size_t ws_size,
                              hipStream_t stream) {
  const float* x    = (const float*)d_in[0];
  const float* srr  = (const float*)d_in[1];
  const float* sim  = (const float*)d_in[2];
  const float* traw = (const float*)d_in[3];
  const float* W    = (const float*)d_in[4];
  const float* bias = (const float*)d_in[5];
  float* out = (float*)d_out;

  // ws layout (floats): consts[4096] | U(bf16: Msz*Ksz ushorts = 8388608 fl)
  //   | carry[524288] | prefix[524288] | WfH[65536] | WfL[65536]
  //   | partial_v[8192] | wv[256]
  float* wsf    = (float*)d_ws;
  float* consts = wsf;
  unsigned short* U = (unsigned short*)(wsf + 4096);
  float* carry  = wsf + 4096 + 8388608;
  float* prefix = carry + (size_t)2 * Bsz * NCH * Ksz;
  unsigned int* WfH = (unsigned int*)(prefix + (size_t)2 * Bsz * NCH * Ksz);
  unsigned int* WfL = WfH + 65536;
  float* partial_v  = (float*)(WfL + 65536);
  float* wv         = partial_v + 16 * Dsz;

  prep1_kernel<<<16, 512, 0, stream>>>(W, partial_v);
  prep2_kernel<<<64, 512, 0, stream>>>(W, partial_v, wv);
  prep3_kernel<<<1, 256, 0, stream>>>(srr, sim, traw, wv, consts);
  wpack_kernel<<<256, 64, 0, stream>>>(W, consts, WfH, WfL);
  gemm_mfma<<<Msz / 64, 256, 0, stream>>>(x, WfH, WfL, bias, consts, U, carry);
  scan_prefix<<<dim3(Bsz, Ksz / 64), 64, 0, stream>>>(consts, carry, prefix);
  scan_final<<<Bsz * NCH, Ksz, 0, stream>>>(U, consts, prefix, out);
}

// Round 14
// 113.851 us; speedup vs baseline: 1.1652x; 1.1309x over previous
//
#include <hip/hip_runtime.h>

#define Bsz 16
#define Tsz 4096
#define Dsz 512
#define Ksz 256
#define Msz (Bsz * Tsz)      // 65536
#define CHUNK 64
#define NCH (Tsz / CHUNK)    // 64

typedef __attribute__((ext_vector_type(8))) short short8;
typedef __attribute__((ext_vector_type(4))) float f32x4;

// ---------------- threefry2x32 (key = (0, 42)) — matches JAX exactly -------
__device__ __forceinline__ unsigned int rotl32(unsigned int x, int d) {
  return (x << d) | (x >> (32 - d));
}

__device__ void threefry_pair(unsigned int c0, unsigned int c1,
                              unsigned int& o0, unsigned int& o1) {
  const unsigned int k0 = 0u, k1 = 42u;
  const unsigned int k2 = k0 ^ k1 ^ 0x1BD11BDAu;
  unsigned int x0 = c0 + k0;
  unsigned int x1 = c1 + k1;
#define TF_ROUND(r) { x0 += x1; x1 = rotl32(x1, (r)); x1 ^= x0; }
  TF_ROUND(13) TF_ROUND(15) TF_ROUND(26) TF_ROUND(6)
  x0 += k1; x1 += k2 + 1u;
  TF_ROUND(17) TF_ROUND(29) TF_ROUND(16) TF_ROUND(24)
  x0 += k2; x1 += k0 + 2u;
  TF_ROUND(13) TF_ROUND(15) TF_ROUND(26) TF_ROUND(6)
  x0 += k0; x1 += k1 + 3u;
  TF_ROUND(17) TF_ROUND(29) TF_ROUND(16) TF_ROUND(24)
  x0 += k1; x1 += k2 + 4u;
  TF_ROUND(13) TF_ROUND(15) TF_ROUND(26) TF_ROUND(6)
  x0 += k2; x1 += k0 + 5u;
#undef TF_ROUND
  o0 = x0; o1 = x1;
}

// XLA ErfInv32 polynomial (math.cc)
__device__ float erfinv32(float x) {
  float w = -log1pf(-x * x);
  float p;
  if (w < 5.f) {
    w -= 2.5f;
    p = 2.81022636e-08f;
    p = fmaf(p, w, 3.43273939e-07f);
    p = fmaf(p, w, -3.5233877e-06f);
    p = fmaf(p, w, -4.39150654e-06f);
    p = fmaf(p, w, 0.00021858087f);
    p = fmaf(p, w, -0.00125372503f);
    p = fmaf(p, w, -0.00417768164f);
    p = fmaf(p, w, 0.246640727f);
    p = fmaf(p, w, 1.50140941f);
  } else {
    w = sqrtf(w) - 3.f;
    p = -0.000200214257f;
    p = fmaf(p, w, 0.000100950558f);
    p = fmaf(p, w, 0.00134934322f);
    p = fmaf(p, w, -0.00367342844f);
    p = fmaf(p, w, 0.00573950773f);
    p = fmaf(p, w, -0.0076224613f);
    p = fmaf(p, w, 0.00943887047f);
    p = fmaf(p, w, 1.00167406f);
    p = fmaf(p, w, 2.83297682f);
  }
  return p * x;
}

// JAX: bits -> uniform[-0.99999994, 1) -> sqrt(2)*erfinv
__device__ float bits_to_normal(unsigned int bits) {
  unsigned int fb = (bits >> 9) | 0x3f800000u;
  float f = __uint_as_float(fb) - 1.0f;   // [0,1)
  const float lo = -0.99999994f;          // nextafter(-1, 0) in f32
  float u = f * 2.0f + lo;                // hi - lo rounds to exactly 2.0f
  u = fmaxf(lo, u);
  return 1.41421356f * erfinv32(u);
}

__device__ float block_sum_512(float v, float* s_red) {
  #pragma unroll
  for (int o = 32; o > 0; o >>= 1) v += __shfl_down(v, o);
  const int lane = threadIdx.x & 63, wid = threadIdx.x >> 6;
  if (lane == 0) s_red[wid] = v;
  __syncthreads();
  float r = 0.f;
  #pragma unroll
  for (int i = 0; i < 8; ++i) r += s_red[i];
  __syncthreads();
  return r;
}

__device__ __forceinline__ unsigned int bf16rne(float f) {
  unsigned int u = __float_as_uint(f);
  return (u + 0x7FFFu + ((u >> 16) & 1u)) >> 16;
}

// split 2 floats -> packed hi-trunc (1 v_perm) + packed lo-RNE (v_cvt_pk,
// RNE == bf16rne; src0 -> low16, src1 -> high16: matches prior packing)
__device__ __forceinline__ void split2(float v0, float v1,
                                       unsigned int& hh, unsigned int& ll) {
  unsigned int u0 = __float_as_uint(v0);
  unsigned int u1 = __float_as_uint(v1);
  hh = __builtin_amdgcn_perm(u1, u0, 0x07060302u);   // [u1.hi16 | u0.hi16]
  float r0 = v0 - __uint_as_float(u0 & 0xFFFF0000u);
  float r1 = v1 - __uint_as_float(u1 & 0xFFFF0000u);
  unsigned int r;
  asm("v_cvt_pk_bf16_f32 %0, %1, %2" : "=v"(r) : "v"(r0), "v"(r1));
  ll = r;
}

// --------- prep1 (16 blocks x 512): partial_v[b][d] = sum_k W[k][d]*u0n[k] --
__global__ __launch_bounds__(512) void prep1_kernel(
    const float* __restrict__ W, float* __restrict__ partial_v) {
  __shared__ float s_u0[Ksz];
  __shared__ float s_red[8];
  const int tid = threadIdx.x;
  if (tid < 128) {
    unsigned int y0, y1;
    threefry_pair((unsigned int)tid, (unsigned int)(tid + 128), y0, y1);
    s_u0[tid] = bits_to_normal(y0);
    s_u0[tid + 128] = bits_to_normal(y1);
  }
  __syncthreads();
  float val = (tid < Ksz) ? s_u0[tid] * s_u0[tid] : 0.f;
  float ss = block_sum_512(val, s_red);
  float inv = 1.f / fmaxf(sqrtf(ss), 1e-7f);

  const int k0 = blockIdx.x * 16;
  float acc = 0.f;
  #pragma unroll
  for (int kk = 0; kk < 16; ++kk)
    acc = fmaf(W[(size_t)(k0 + kk) * Dsz + tid], s_u0[k0 + kk], acc);
  partial_v[blockIdx.x * Dsz + tid] = acc * inv;
}

// --------- prep2 (64 blocks x 512): v = normalize(sum partials); wv rows ---
__global__ __launch_bounds__(512) void prep2_kernel(
    const float* __restrict__ W, const float* __restrict__ partial_v,
    float* __restrict__ wv) {
  __shared__ float s_v[Dsz];
  __shared__ float s_red[8];
  __shared__ float s_p[8];
  const int tid = threadIdx.x;
  float acc = 0.f;
  #pragma unroll
  for (int b = 0; b < 16; ++b) acc += partial_v[b * Dsz + tid];
  float ssv = block_sum_512(acc * acc, s_red);
  float invv = 1.f / fmaxf(sqrtf(ssv), 1e-7f);
  s_v[tid] = acc * invv;
  __syncthreads();

  const int k = blockIdx.x * 4 + (tid >> 7);
  const int sub = tid & 127;
  const float* wr = W + (size_t)k * Dsz;
  float p = 0.f;
  #pragma unroll
  for (int j = sub; j < Dsz; j += 128) p = fmaf(wr[j], s_v[j], p);
  #pragma unroll
  for (int o = 32; o > 0; o >>= 1) p += __shfl_down(p, o);
  const int lane = tid & 63, wid = tid >> 6;
  if (lane == 0) s_p[wid] = p;
  __syncthreads();
  if (tid < 4) wv[blockIdx.x * 4 + tid] = s_p[2 * tid] + s_p[2 * tid + 1];
}

// --------- prep3 (1 block x 256): sigma + all per-k constants --------------
// consts layout (floats): [0]=ar [K]=ai [2K]=A64r [3K]=A64i [4K]=P4r [5K]=P4i
//   [6K]=P8r [7K]=P8i [8K]=P16r [9K]=P16i [10K]=P32r [11K]=P32i [12K]=inv_sigma
__global__ __launch_bounds__(256) void prep3_kernel(
    const float* __restrict__ s_real_raw, const float* __restrict__ s_imag,
    const float* __restrict__ tau_raw, const float* __restrict__ wv,
    float* __restrict__ consts) {
  __shared__ float s_p[4];
  const int tid = threadIdx.x;
  float v = wv[tid];
  float v2 = v * v;
  #pragma unroll
  for (int o = 32; o > 0; o >>= 1) v2 += __shfl_down(v2, o);
  const int lane = tid & 63, wid = tid >> 6;
  if (lane == 0) s_p[wid] = v2;
  __syncthreads();
  float sswv = s_p[0] + s_p[1] + s_p[2] + s_p[3];
  float sigma = sswv / fmaxf(sqrtf(sswv), 1e-7f);
  if (tid == 0) consts[12 * Ksz] = 1.f / sigma;

  float tr = tau_raw[0];
  float tau = fmaxf(tr, 0.f) + log1pf(expf(-fabsf(tr))) + 1e-3f;
  float srr = s_real_raw[tid];
  float sp = fmaxf(srr, 0.f) + log1pf(expf(-fabsf(srr)));
  float alpha0 = (sp + 1e-6f) * tau;
  float omega0 = s_imag[tid] * tau;
  const float dt = 1.f / 4095.f;
  float ad = alpha0 * dt, an = omega0 * dt;
  consts[tid]            = expf(-ad) * cosf(an);
  consts[Ksz + tid]      = expf(-ad) * sinf(an);
  consts[2 * Ksz + tid]  = expf(-ad * 64.f) * cosf(an * 64.f);
  consts[3 * Ksz + tid]  = expf(-ad * 64.f) * sinf(an * 64.f);
  consts[4 * Ksz + tid]  = expf(-ad * 4.f) * cosf(an * 4.f);
  consts[5 * Ksz + tid]  = expf(-ad * 4.f) * sinf(an * 4.f);
  consts[6 * Ksz + tid]  = expf(-ad * 8.f) * cosf(an * 8.f);
  consts[7 * Ksz + tid]  = expf(-ad * 8.f) * sinf(an * 8.f);
  consts[8 * Ksz + tid]  = expf(-ad * 16.f) * cosf(an * 16.f);
  consts[9 * Ksz + tid]  = expf(-ad * 16.f) * sinf(an * 16.f);
  consts[10 * Ksz + tid] = expf(-ad * 32.f) * cosf(an * 32.f);
  consts[11 * Ksz + tid] = expf(-ad * 32.f) * sinf(an * 32.f);
}

// --------- wpack: W/sigma -> bf16 h/l in MFMA B-fragment order -------------
__global__ __launch_bounds__(64) void wpack_kernel(
    const float* __restrict__ W, const float* __restrict__ consts,
    unsigned int* __restrict__ WfH, unsigned int* __restrict__ WfL) {
  const int kb = blockIdx.x >> 4;
  const int nb = blockIdx.x & 15;
  const int lane = threadIdx.x;
  const int lr = lane & 15, lg = lane >> 4;
  const float inv_sigma = consts[12 * Ksz];
  const float* src = W + (size_t)(nb * 16 + lr) * Dsz + kb * 32 + lg * 8;
  float v[8];
  *(float4*)&v[0] = *(const float4*)src;
  *(float4*)&v[4] = *(const float4*)(src + 4);
  unsigned int hh[4], ll[4];
  #pragma unroll
  for (int i = 0; i < 4; ++i)
    split2(v[2 * i] * inv_sigma, v[2 * i + 1] * inv_sigma, hh[i], ll[i]);
  const size_t off = (size_t)blockIdx.x * 256 + lane * 4;   // in uints
  *(int4*)(WfH + off) = *(int4*)hh;
  *(int4*)(WfL + off) = *(int4*)ll;
}

// --------- MFMA GEMM + fused chunk-scan carry ------------------------------
// BM=128 (= 2 scan chunks), BN=256, BK=32. 512 threads = 8 waves (2m x 4n):
// round-10 proven schedule (best known: 81us): B reg-dbuf issued early,
// staging-thread convert (1x total, now perm+cvt_pk = fewer VALU,
// bit-identical), LDS dbuf, single lgkm-drain barrier per phase.
// U stored bf16. Epilogue: per-wave 64-row carry, chunk = 2*blockIdx + wm.
__global__ __launch_bounds__(512, 2) void gemm_mfma(
    const float* __restrict__ X, const unsigned int* __restrict__ WfH,
    const unsigned int* __restrict__ WfL, const float* __restrict__ bias,
    const float* __restrict__ consts, unsigned short* __restrict__ U,
    float* __restrict__ carry) {
  __shared__ unsigned int ldsA[2][4096];   // 2 x 16KB: 128 rows x [64B h|64B l]

  const int tid = threadIdx.x;
  const size_t m0 = (size_t)blockIdx.x * 128;

  // A staging: thread -> (row sr = tid>>2, k-chunk sc = (tid&3)*8 floats)
  const int sr = tid >> 2;              // 0..127
  const int sc = (tid & 3) * 8;
  const float* gx = X + (m0 + sr) * Dsz + sc;
  const int swz = (sr & 7) << 4;
  const int aoff_h = sr * 128 + ((sc * 2) ^ swz);
  const int aoff_l = sr * 128 + ((64 + sc * 2) ^ swz);

  const int lane = tid & 63;
  const int wid = tid >> 6;             // 0..7
  const int wm = wid >> 2;              // 0..1 -> rows wm*64
  const int wn = wid & 3;               // 0..3 -> cols wn*64
  const int lr = lane & 15;
  const int lg = lane >> 4;

  float xaA[8], xaB[8];
  #define LOAD_A(dst, kb) do {                             \
    const float* p = gx + (kb) * 32;                       \
    *(float4*)&dst[0] = *(const float4*)p;                 \
    *(float4*)&dst[4] = *(const float4*)(p + 4);           \
  } while (0)

  const char* const wfh = (const char*)WfH + (size_t)wn * 4096 + lane * 16;
  const char* const wfl = (const char*)WfL + (size_t)wn * 4096 + lane * 16;

  short8 bhA[4], blA[4], bhB[4], blB[4];
  #define LOAD_B(bh_, bl_, kb) do {                                          \
    const size_t tb = (size_t)(kb) * 16384;                                  \
    _Pragma("unroll")                                                        \
    for (int f = 0; f < 4; ++f) {                                            \
      bh_[f] = *(const short8*)(wfh + tb + (size_t)f * 1024);                \
      bl_[f] = *(const short8*)(wfl + tb + (size_t)f * 1024);                \
    }                                                                        \
  } while (0)

  #define CONVERT_STORE(xa, buf) do {                                        \
    char* const Ab_ = (char*)ldsA[(buf)];                                    \
    unsigned int hh[4], llw[4];                                              \
    _Pragma("unroll")                                                        \
    for (int i = 0; i < 4; ++i)                                              \
      split2(xa[2 * i], xa[2 * i + 1], hh[i], llw[i]);                       \
    *(int4*)(Ab_ + aoff_h) = *(int4*)hh;                                     \
    *(int4*)(Ab_ + aoff_l) = *(int4*)llw;                                    \
  } while (0)

  short8 ah[4], al[4];
  #define DS_READ(buf) do {                                                  \
    const char* const Ab_ = (const char*)ldsA[(buf)];                        \
    _Pragma("unroll")                                                        \
    for (int f = 0; f < 4; ++f) {                                            \
      const int r = wm * 64 + f * 16 + lr;                                   \
      const int sz = (r & 7) << 4;                                           \
      ah[f] = *(const short8*)(Ab_ + r * 128 + ((lg * 16) ^ sz));            \
      al[f] = *(const short8*)(Ab_ + r * 128 + ((64 + lg * 16) ^ sz));       \
    }                                                                        \
  } while (0)

  f32x4 acc[4][4];
  #pragma unroll
  for (int i = 0; i < 4; ++i)
    #pragma unroll
    for (int j = 0; j < 4; ++j) acc[i][j] = (f32x4)(0.f);

  #define MFMA48(bh_, bl_) do {                                              \
    _Pragma("unroll")                                                        \
    for (int mf = 0; mf < 4; ++mf)                                           \
      _Pragma("unroll")                                                      \
      for (int nf = 0; nf < 4; ++nf)                                         \
        acc[mf][nf] = __builtin_amdgcn_mfma_f32_16x16x32_bf16(               \
            ah[mf], bh_[nf], acc[mf][nf], 0, 0, 0);                          \
    _Pragma("unroll")                                                        \
    for (int mf = 0; mf < 4; ++mf)                                           \
      _Pragma("unroll")                                                      \
      for (int nf = 0; nf < 4; ++nf)                                         \
        acc[mf][nf] = __builtin_amdgcn_mfma_f32_16x16x32_bf16(               \
            ah[mf], bl_[nf], acc[mf][nf], 0, 0, 0);                          \
    _Pragma("unroll")                                                        \
    for (int mf = 0; mf < 4; ++mf)                                           \
      _Pragma("unroll")                                                      \
      for (int nf = 0; nf < 4; ++nf)                                         \
        acc[mf][nf] = __builtin_amdgcn_mfma_f32_16x16x32_bf16(               \
            al[mf], bh_[nf], acc[mf][nf], 0, 0, 0);                          \
  } while (0)

  #define SYNC() do {                                                        \
    asm volatile("s_waitcnt lgkmcnt(0)" ::: "memory");                       \
    __builtin_amdgcn_s_barrier();                                            \
    __builtin_amdgcn_sched_barrier(0);                                       \
  } while (0)

  // prologue (round-5): raw A 2-deep, B 1-ahead
  LOAD_A(xaA, 0);
  LOAD_A(xaB, 1);
  LOAD_B(bhA, blA, 0);

  #define BODY(kb, xa, bhC, blC, bhN, blN) do {                              \
    if ((kb) + 1 < 16) LOAD_B(bhN, blN, (kb) + 1);   /* issue B early */     \
    CONVERT_STORE(xa, (kb) & 1);                                             \
    if ((kb) + 2 < 16) LOAD_A(xa, (kb) + 2);         /* 2-deep A */          \
    SYNC();                                                                  \
    DS_READ((kb) & 1);                                                       \
    MFMA48(bhC, blC);                                                        \
  } while (0)

  for (int kb = 0; kb < 16; kb += 2) {
    BODY(kb,     xaA, bhA, blA, bhB, blB);
    BODY(kb + 1, xaB, bhB, blB, bhA, blA);
  }
  #undef BODY
  #undef SYNC
  #undef MFMA48
  #undef DS_READ
  #undef CONVERT_STORE
  #undef LOAD_B
  #undef LOAD_A

  // ---- epilogue: bf16 U store + fused 64-row chunk carry ----
  // wave's rows = one chunk (index 2*blockIdx+wm): t = mf*16 + lg*4 + j,
  // weight a^{63-t} = P4^{3-lg} * P16^{3-mf} * a^{3-j}
  #pragma unroll
  for (int nf = 0; nf < 4; ++nf) {
    const int n = wn * 64 + nf * 16 + lr;
    const float bv = bias[n];
    const float ar_ = consts[n],           ai_ = consts[Ksz + n];
    const float p4r = consts[4 * Ksz + n], p4i = consts[5 * Ksz + n];
    const float p8r = consts[6 * Ksz + n], p8i = consts[7 * Ksz + n];
    const float p16r = consts[8 * Ksz + n], p16i = consts[9 * Ksz + n];
    const int e = 3 - lg;
    const float b1r = (e & 1) ? p4r : 1.f, b1i = (e & 1) ? p4i : 0.f;
    const float b2r = (e & 2) ? p8r : 1.f, b2i = (e & 2) ? p8i : 0.f;
    float wr = b1r * b2r - b1i * b2i;
    float wi = b1r * b2i + b1i * b2r;
    float Sr = 0.f, Si = 0.f;
    #pragma unroll
    for (int mf = 3; mf >= 0; --mf) {
      float vr = wr, vi = wi;
      #pragma unroll
      for (int j = 3; j >= 0; --j) {
        const float u = acc[mf][nf][j] + bv;
        U[(m0 + wm * 64 + mf * 16 + lg * 4 + j) * Ksz + n] =
            (unsigned short)bf16rne(u);
        Sr = fmaf(u, vr, Sr);
        Si = fmaf(u, vi, Si);
        if (j) {
          float t_ = vr * ar_ - vi * ai_;
          vi = vr * ai_ + vi * ar_;
          vr = t_;
        }
      }
      if (mf) {
        float t_ = wr * p16r - wi * p16i;
        wi = wr * p16i + wi * p16r;
        wr = t_;
      }
    }
    Sr += __shfl_xor(Sr, 16); Si += __shfl_xor(Si, 16);
    Sr += __shfl_xor(Sr, 32); Si += __shfl_xor(Si, 32);
    if (lg == 0)
      ((float2*)carry)[(size_t)(blockIdx.x * 2 + wm) * Ksz + n] =
          make_float2(Sr, Si);
  }
}

// --------- scan pass 2: exclusive prefix over chunks (A = a^64) ------------
__global__ __launch_bounds__(64) void scan_prefix(
    const float* __restrict__ consts, const float* __restrict__ carry,
    float* __restrict__ prefix) {
  const int k = blockIdx.y * 64 + threadIdx.x;
  const int b = blockIdx.x;
  const float Ar = consts[2 * Ksz + k], Ai = consts[3 * Ksz + k];
  const float2* cp = (const float2*)carry;
  float2* pp = (float2*)prefix;
  float c = 0.f, s = 0.f;
  for (int m = 0; m < NCH; ++m) {
    const size_t idx = (size_t)(b * NCH + m) * Ksz + k;
    pp[idx] = make_float2(c, s);
    float2 L = cp[idx];
    float cn = fmaf(Ar, c, fmaf(-Ai, s, L.x));
    float sn = fmaf(Ai, c, fmaf(Ar, s, L.y));
    c = cn; s = sn;
  }
}

// --------- scan pass 3: rescan chunk from true carry, write output ---------
// 4 k's per thread: u64 U-loads (8B/lane) + float4 stores (16B/lane).
// Per-k math and order identical to prior rounds.
__global__ __launch_bounds__(256) void scan_final(
    const unsigned short* __restrict__ U, const float* __restrict__ consts,
    const float* __restrict__ prefix, float* __restrict__ out) {
  const int tid = threadIdx.x;
  const int bm = blockIdx.x * 4 + (tid >> 6);
  const int k0 = (tid & 63) * 4;
  float ar[4], ai[4], c[4], s[4];
  #pragma unroll
  for (int j = 0; j < 4; ++j) {
    ar[j] = consts[k0 + j];
    ai[j] = consts[Ksz + k0 + j];
    float2 w = ((const float2*)prefix)[(size_t)bm * Ksz + k0 + j];
    c[j] = w.x; s[j] = w.y;
  }
  const unsigned short* up = U + (size_t)bm * (CHUNK * Ksz) + k0;
  float* op = out + (size_t)bm * (CHUNK * 2 * Ksz) + k0;
  for (int t = 0; t < CHUNK; ++t) {
    unsigned long long uv = *(const unsigned long long*)(up + (size_t)t * Ksz);
    #pragma unroll
    for (int j = 0; j < 4; ++j) {
      float u = __uint_as_float(((unsigned int)(uv >> (16 * j))) << 16);
      float cn = fmaf(ar[j], c[j], fmaf(-ai[j], s[j], u));
      s[j] = fmaf(ai[j], c[j], ar[j] * s[j]);
      c[j] = cn;
    }
    *(float4*)(op + (size_t)t * 2 * Ksz) = make_float4(c[0], c[1], c[2], c[3]);
    *(float4*)(op + (size_t)t * 2 * Ksz + Ksz) =
        make_float4(s[0], s[1], s[2], s[3]);
  }
}

extern "C" void kernel_launch(void* const* d_in, const int* in_sizes, int n_in,
                              void* d_out, int out_size, void* d_ws, size_t ws_size,
                              hipStream_t stream) {
  const float* x    = (const float*)d_in[0];
  const float* srr  = (const float*)d_in[1];
  const float* sim  = (const float*)d_in[2];
  const float* traw = (const float*)d_in[3];
  const float* W    = (const float*)d_in[4];
  const float* bias = (const float*)d_in[5];
  float* out = (float*)d_out;

  // ws layout (floats): consts[4096] | U(bf16: Msz*Ksz ushorts = 8388608 fl)
  //   | carry[524288] | prefix[524288] | WfH[65536] | WfL[65536]
  //   | partial_v[8192] | wv[256]
  float* wsf    = (float*)d_ws;
  float* consts = wsf;
  unsigned short* U = (unsigned short*)(wsf + 4096);
  float* carry  = wsf + 4096 + 8388608;
  float* prefix = carry + (size_t)2 * Bsz * NCH * Ksz;
  unsigned int* WfH = (unsigned int*)(prefix + (size_t)2 * Bsz * NCH * Ksz);
  unsigned int* WfL = WfH + 65536;
  float* partial_v  = (float*)(WfL + 65536);
  float* wv         = partial_v + 16 * Dsz;

  prep1_kernel<<<16, 512, 0, stream>>>(W, partial_v);
  prep2_kernel<<<64, 512, 0, stream>>>(W, partial_v, wv);
  prep3_kernel<<<1, 256, 0, stream>>>(srr, sim, traw, wv, consts);
  wpack_kernel<<<256, 64, 0, stream>>>(W, consts, WfH, WfL);
  gemm_mfma<<<Msz / 128, 512, 0, stream>>>(x, WfH, WfL, bias, consts, U, carry);
  scan_prefix<<<dim3(Bsz, Ksz / 64), 64, 0, stream>>>(consts, carry, prefix);
  scan_final<<<Bsz * NCH / 4, 256, 0, stream>>>(U, consts, prefix, out);
}

// Round 15
// 112.611 us; speedup vs baseline: 1.1781x; 1.0110x over previous
//
#include <hip/hip_runtime.h>

#define Bsz 16
#define Tsz 4096
#define Dsz 512
#define Ksz 256
#define Msz (Bsz * Tsz)      // 65536
#define CHUNK 64
#define NCH (Tsz / CHUNK)    // 64

typedef __attribute__((ext_vector_type(8))) short short8;
typedef __attribute__((ext_vector_type(4))) float f32x4;

// ---------------- threefry2x32 (key = (0, 42)) — matches JAX exactly -------
__device__ __forceinline__ unsigned int rotl32(unsigned int x, int d) {
  return (x << d) | (x >> (32 - d));
}

__device__ void threefry_pair(unsigned int c0, unsigned int c1,
                              unsigned int& o0, unsigned int& o1) {
  const unsigned int k0 = 0u, k1 = 42u;
  const unsigned int k2 = k0 ^ k1 ^ 0x1BD11BDAu;
  unsigned int x0 = c0 + k0;
  unsigned int x1 = c1 + k1;
#define TF_ROUND(r) { x0 += x1; x1 = rotl32(x1, (r)); x1 ^= x0; }
  TF_ROUND(13) TF_ROUND(15) TF_ROUND(26) TF_ROUND(6)
  x0 += k1; x1 += k2 + 1u;
  TF_ROUND(17) TF_ROUND(29) TF_ROUND(16) TF_ROUND(24)
  x0 += k2; x1 += k0 + 2u;
  TF_ROUND(13) TF_ROUND(15) TF_ROUND(26) TF_ROUND(6)
  x0 += k0; x1 += k1 + 3u;
  TF_ROUND(17) TF_ROUND(29) TF_ROUND(16) TF_ROUND(24)
  x0 += k1; x1 += k2 + 4u;
  TF_ROUND(13) TF_ROUND(15) TF_ROUND(26) TF_ROUND(6)
  x0 += k2; x1 += k0 + 5u;
#undef TF_ROUND
  o0 = x0; o1 = x1;
}

// XLA ErfInv32 polynomial (math.cc)
__device__ float erfinv32(float x) {
  float w = -log1pf(-x * x);
  float p;
  if (w < 5.f) {
    w -= 2.5f;
    p = 2.81022636e-08f;
    p = fmaf(p, w, 3.43273939e-07f);
    p = fmaf(p, w, -3.5233877e-06f);
    p = fmaf(p, w, -4.39150654e-06f);
    p = fmaf(p, w, 0.00021858087f);
    p = fmaf(p, w, -0.00125372503f);
    p = fmaf(p, w, -0.00417768164f);
    p = fmaf(p, w, 0.246640727f);
    p = fmaf(p, w, 1.50140941f);
  } else {
    w = sqrtf(w) - 3.f;
    p = -0.000200214257f;
    p = fmaf(p, w, 0.000100950558f);
    p = fmaf(p, w, 0.00134934322f);
    p = fmaf(p, w, -0.00367342844f);
    p = fmaf(p, w, 0.00573950773f);
    p = fmaf(p, w, -0.0076224613f);
    p = fmaf(p, w, 0.00943887047f);
    p = fmaf(p, w, 1.00167406f);
    p = fmaf(p, w, 2.83297682f);
  }
  return p * x;
}

// JAX: bits -> uniform[-0.99999994, 1) -> sqrt(2)*erfinv
__device__ float bits_to_normal(unsigned int bits) {
  unsigned int fb = (bits >> 9) | 0x3f800000u;
  float f = __uint_as_float(fb) - 1.0f;   // [0,1)
  const float lo = -0.99999994f;          // nextafter(-1, 0) in f32
  float u = f * 2.0f + lo;                // hi - lo rounds to exactly 2.0f
  u = fmaxf(lo, u);
  return 1.41421356f * erfinv32(u);
}

__device__ float block_sum_512(float v, float* s_red) {
  #pragma unroll
  for (int o = 32; o > 0; o >>= 1) v += __shfl_down(v, o);
  const int lane = threadIdx.x & 63, wid = threadIdx.x >> 6;
  if (lane == 0) s_red[wid] = v;
  __syncthreads();
  float r = 0.f;
  #pragma unroll
  for (int i = 0; i < 8; ++i) r += s_red[i];
  __syncthreads();
  return r;
}

__device__ __forceinline__ unsigned int bf16rne(float f) {
  unsigned int u = __float_as_uint(f);
  return (u + 0x7FFFu + ((u >> 16) & 1u)) >> 16;
}

// split 2 floats -> packed hi-trunc (1 v_perm) + packed lo-RNE (v_cvt_pk,
// RNE == bf16rne; src0 -> low16, src1 -> high16: matches prior packing)
__device__ __forceinline__ void split2(float v0, float v1,
                                       unsigned int& hh, unsigned int& ll) {
  unsigned int u0 = __float_as_uint(v0);
  unsigned int u1 = __float_as_uint(v1);
  hh = __builtin_amdgcn_perm(u1, u0, 0x07060302u);   // [u1.hi16 | u0.hi16]
  float r0 = v0 - __uint_as_float(u0 & 0xFFFF0000u);
  float r1 = v1 - __uint_as_float(u1 & 0xFFFF0000u);
  unsigned int r;
  asm("v_cvt_pk_bf16_f32 %0, %1, %2" : "=v"(r) : "v"(r0), "v"(r1));
  ll = r;
}

// --------- prep1 (16 blocks x 512): partial_v[b][d] = sum_k W[k][d]*u0n[k] --
__global__ __launch_bounds__(512) void prep1_kernel(
    const float* __restrict__ W, float* __restrict__ partial_v) {
  __shared__ float s_u0[Ksz];
  __shared__ float s_red[8];
  const int tid = threadIdx.x;
  if (tid < 128) {
    unsigned int y0, y1;
    threefry_pair((unsigned int)tid, (unsigned int)(tid + 128), y0, y1);
    s_u0[tid] = bits_to_normal(y0);
    s_u0[tid + 128] = bits_to_normal(y1);
  }
  __syncthreads();
  float val = (tid < Ksz) ? s_u0[tid] * s_u0[tid] : 0.f;
  float ss = block_sum_512(val, s_red);
  float inv = 1.f / fmaxf(sqrtf(ss), 1e-7f);

  const int k0 = blockIdx.x * 16;
  float acc = 0.f;
  #pragma unroll
  for (int kk = 0; kk < 16; ++kk)
    acc = fmaf(W[(size_t)(k0 + kk) * Dsz + tid], s_u0[k0 + kk], acc);
  partial_v[blockIdx.x * Dsz + tid] = acc * inv;
}

// --------- prep2 (64 blocks x 512): v = normalize(sum partials); wv rows ---
__global__ __launch_bounds__(512) void prep2_kernel(
    const float* __restrict__ W, const float* __restrict__ partial_v,
    float* __restrict__ wv) {
  __shared__ float s_v[Dsz];
  __shared__ float s_red[8];
  __shared__ float s_p[8];
  const int tid = threadIdx.x;
  float acc = 0.f;
  #pragma unroll
  for (int b = 0; b < 16; ++b) acc += partial_v[b * Dsz + tid];
  float ssv = block_sum_512(acc * acc, s_red);
  float invv = 1.f / fmaxf(sqrtf(ssv), 1e-7f);
  s_v[tid] = acc * invv;
  __syncthreads();

  const int k = blockIdx.x * 4 + (tid >> 7);
  const int sub = tid & 127;
  const float* wr = W + (size_t)k * Dsz;
  float p = 0.f;
  #pragma unroll
  for (int j = sub; j < Dsz; j += 128) p = fmaf(wr[j], s_v[j], p);
  #pragma unroll
  for (int o = 32; o > 0; o >>= 1) p += __shfl_down(p, o);
  const int lane = tid & 63, wid = tid >> 6;
  if (lane == 0) s_p[wid] = p;
  __syncthreads();
  if (tid < 4) wv[blockIdx.x * 4 + tid] = s_p[2 * tid] + s_p[2 * tid + 1];
}

// --------- prep3 (1 block x 256): sigma + all per-k constants --------------
// consts layout (floats): [0]=ar [K]=ai [2K]=A64r [3K]=A64i [4K]=P4r [5K]=P4i
//   [6K]=P8r [7K]=P8i [8K]=P16r [9K]=P16i [10K]=P32r [11K]=P32i [12K]=inv_sigma
__global__ __launch_bounds__(256) void prep3_kernel(
    const float* __restrict__ s_real_raw, const float* __restrict__ s_imag,
    const float* __restrict__ tau_raw, const float* __restrict__ wv,
    float* __restrict__ consts) {
  __shared__ float s_p[4];
  const int tid = threadIdx.x;
  float v = wv[tid];
  float v2 = v * v;
  #pragma unroll
  for (int o = 32; o > 0; o >>= 1) v2 += __shfl_down(v2, o);
  const int lane = tid & 63, wid = tid >> 6;
  if (lane == 0) s_p[wid] = v2;
  __syncthreads();
  float sswv = s_p[0] + s_p[1] + s_p[2] + s_p[3];
  float sigma = sswv / fmaxf(sqrtf(sswv), 1e-7f);
  if (tid == 0) consts[12 * Ksz] = 1.f / sigma;

  float tr = tau_raw[0];
  float tau = fmaxf(tr, 0.f) + log1pf(expf(-fabsf(tr))) + 1e-3f;
  float srr = s_real_raw[tid];
  float sp = fmaxf(srr, 0.f) + log1pf(expf(-fabsf(srr)));
  float alpha0 = (sp + 1e-6f) * tau;
  float omega0 = s_imag[tid] * tau;
  const float dt = 1.f / 4095.f;
  float ad = alpha0 * dt, an = omega0 * dt;
  consts[tid]            = expf(-ad) * cosf(an);
  consts[Ksz + tid]      = expf(-ad) * sinf(an);
  consts[2 * Ksz + tid]  = expf(-ad * 64.f) * cosf(an * 64.f);
  consts[3 * Ksz + tid]  = expf(-ad * 64.f) * sinf(an * 64.f);
  consts[4 * Ksz + tid]  = expf(-ad * 4.f) * cosf(an * 4.f);
  consts[5 * Ksz + tid]  = expf(-ad * 4.f) * sinf(an * 4.f);
  consts[6 * Ksz + tid]  = expf(-ad * 8.f) * cosf(an * 8.f);
  consts[7 * Ksz + tid]  = expf(-ad * 8.f) * sinf(an * 8.f);
  consts[8 * Ksz + tid]  = expf(-ad * 16.f) * cosf(an * 16.f);
  consts[9 * Ksz + tid]  = expf(-ad * 16.f) * sinf(an * 16.f);
  consts[10 * Ksz + tid] = expf(-ad * 32.f) * cosf(an * 32.f);
  consts[11 * Ksz + tid] = expf(-ad * 32.f) * sinf(an * 32.f);
}

// --------- wpack: W/sigma -> bf16 h/l in MFMA B-fragment order -------------
__global__ __launch_bounds__(64) void wpack_kernel(
    const float* __restrict__ W, const float* __restrict__ consts,
    unsigned int* __restrict__ WfH, unsigned int* __restrict__ WfL) {
  const int kb = blockIdx.x >> 4;
  const int nb = blockIdx.x & 15;
  const int lane = threadIdx.x;
  const int lr = lane & 15, lg = lane >> 4;
  const float inv_sigma = consts[12 * Ksz];
  const float* src = W + (size_t)(nb * 16 + lr) * Dsz + kb * 32 + lg * 8;
  float v[8];
  *(float4*)&v[0] = *(const float4*)src;
  *(float4*)&v[4] = *(const float4*)(src + 4);
  unsigned int hh[4], ll[4];
  #pragma unroll
  for (int i = 0; i < 4; ++i)
    split2(v[2 * i] * inv_sigma, v[2 * i + 1] * inv_sigma, hh[i], ll[i]);
  const size_t off = (size_t)blockIdx.x * 256 + lane * 4;   // in uints
  *(int4*)(WfH + off) = *(int4*)hh;
  *(int4*)(WfL + off) = *(int4*)ll;
}

// --------- MFMA GEMM + fused chunk-scan carry ------------------------------
// BM=128 (= 2 scan chunks), BN=256, BK=32. 512 threads = 8 waves (2m x 4n).
// SUPER-PHASE schedule: 2 K-tiles per barrier via a 4-buffer LDS ring
// (64KB): phase s writes pair (s&1)*2, ONE lgkm-drain + ONE s_barrier, then
// reads+MFMAs both tiles. Ring-4 race-free with a single barrier per phase
// (a wave's reads are consumed before it signals the next barrier; the pair
// it read is rewritten only after that barrier). Halves the 16 per-tile
// walls of the round-10 schedule. U bit-identical (same per-tile MFMA order,
// same tile order). U stored bf16. Epilogue: per-wave 64-row carry.
__global__ __launch_bounds__(512, 2) void gemm_mfma(
    const float* __restrict__ X, const unsigned int* __restrict__ WfH,
    const unsigned int* __restrict__ WfL, const float* __restrict__ bias,
    const float* __restrict__ consts, unsigned short* __restrict__ U,
    float* __restrict__ carry) {
  __shared__ unsigned int ldsA[4][4096];   // 4 bufs x 16KB: 128 rows x [h|l]

  const int tid = threadIdx.x;
  const size_t m0 = (size_t)blockIdx.x * 128;

  // A staging: thread -> (row sr = tid>>2, k-chunk sc = (tid&3)*8 floats)
  const int sr = tid >> 2;              // 0..127
  const int sc = (tid & 3) * 8;
  const float* gx = X + (m0 + sr) * Dsz + sc;
  const int swz = (sr & 7) << 4;
  const int aoff_h = sr * 128 + ((sc * 2) ^ swz);
  const int aoff_l = sr * 128 + ((64 + sc * 2) ^ swz);

  const int lane = tid & 63;
  const int wid = tid >> 6;             // 0..7
  const int wm = wid >> 2;              // 0..1 -> rows wm*64
  const int wn = wid & 3;               // 0..3 -> cols wn*64
  const int lr = lane & 15;
  const int lg = lane >> 4;

  float xaA[8], xaB[8];
  #define LOAD_A(dst, kb) do {                             \
    const float* p = gx + (kb) * 32;                       \
    *(float4*)&dst[0] = *(const float4*)p;                 \
    *(float4*)&dst[4] = *(const float4*)(p + 4);           \
  } while (0)

  const char* const wfh = (const char*)WfH + (size_t)wn * 4096 + lane * 16;
  const char* const wfl = (const char*)WfL + (size_t)wn * 4096 + lane * 16;

  short8 bhA[4], blA[4], bhB[4], blB[4];
  #define LOAD_B(bh_, bl_, kb) do {                                          \
    const size_t tb = (size_t)(kb) * 16384;                                  \
    _Pragma("unroll")                                                        \
    for (int f = 0; f < 4; ++f) {                                            \
      bh_[f] = *(const short8*)(wfh + tb + (size_t)f * 1024);                \
      bl_[f] = *(const short8*)(wfl + tb + (size_t)f * 1024);                \
    }                                                                        \
  } while (0)

  #define CONVERT_STORE(xa, buf) do {                                        \
    char* const Ab_ = (char*)ldsA[(buf)];                                    \
    unsigned int hh[4], llw[4];                                              \
    _Pragma("unroll")                                                        \
    for (int i = 0; i < 4; ++i)                                              \
      split2(xa[2 * i], xa[2 * i + 1], hh[i], llw[i]);                       \
    *(int4*)(Ab_ + aoff_h) = *(int4*)hh;                                     \
    *(int4*)(Ab_ + aoff_l) = *(int4*)llw;                                    \
  } while (0)

  short8 ah[4], al[4];
  #define DS_READ(buf) do {                                                  \
    const char* const Ab_ = (const char*)ldsA[(buf)];                        \
    _Pragma("unroll")                                                        \
    for (int f = 0; f < 4; ++f) {                                            \
      const int r = wm * 64 + f * 16 + lr;                                   \
      const int sz = (r & 7) << 4;                                           \
      ah[f] = *(const short8*)(Ab_ + r * 128 + ((lg * 16) ^ sz));            \
      al[f] = *(const short8*)(Ab_ + r * 128 + ((64 + lg * 16) ^ sz));       \
    }                                                                        \
  } while (0)

  f32x4 acc[4][4];
  #pragma unroll
  for (int i = 0; i < 4; ++i)
    #pragma unroll
    for (int j = 0; j < 4; ++j) acc[i][j] = (f32x4)(0.f);

  #define MFMA48(bh_, bl_) do {                                              \
    _Pragma("unroll")                                                        \
    for (int mf = 0; mf < 4; ++mf)                                           \
      _Pragma("unroll")                                                      \
      for (int nf = 0; nf < 4; ++nf)                                         \
        acc[mf][nf] = __builtin_amdgcn_mfma_f32_16x16x32_bf16(               \
            ah[mf], bh_[nf], acc[mf][nf], 0, 0, 0);                          \
    _Pragma("unroll")                                                        \
    for (int mf = 0; mf < 4; ++mf)                                           \
      _Pragma("unroll")                                                      \
      for (int nf = 0; nf < 4; ++nf)                                         \
        acc[mf][nf] = __builtin_amdgcn_mfma_f32_16x16x32_bf16(               \
            ah[mf], bl_[nf], acc[mf][nf], 0, 0, 0);                          \
    _Pragma("unroll")                                                        \
    for (int mf = 0; mf < 4; ++mf)                                           \
      _Pragma("unroll")                                                      \
      for (int nf = 0; nf < 4; ++nf)                                         \
        acc[mf][nf] = __builtin_amdgcn_mfma_f32_16x16x32_bf16(               \
            al[mf], bh_[nf], acc[mf][nf], 0, 0, 0);                          \
  } while (0)

  #define SYNC() do {                                                        \
    asm volatile("s_waitcnt lgkmcnt(0)" ::: "memory");                       \
    __builtin_amdgcn_s_barrier();                                            \
    __builtin_amdgcn_sched_barrier(0);                                       \
  } while (0)

  // prologue: raw A for tiles 0,1
  LOAD_A(xaA, 0);
  LOAD_A(xaB, 1);

  // SUPER-PHASE s (k0 = 2s, buffer pair p = (s&1)*2):
  //   issue B(k0), B(k0+1); convert+write pair; prefetch A(k0+2),A(k0+3);
  //   ONE drain+barrier; read+MFMA both tiles.
  #define PHASE(k0, p) do {                                                  \
    LOAD_B(bhA, blA, (k0));                                                  \
    LOAD_B(bhB, blB, (k0) + 1);                                              \
    CONVERT_STORE(xaA, (p));                                                 \
    if ((k0) + 2 < 16) LOAD_A(xaA, (k0) + 2);                                \
    CONVERT_STORE(xaB, (p) + 1);                                             \
    if ((k0) + 3 < 16) LOAD_A(xaB, (k0) + 3);                                \
    SYNC();                                                                  \
    DS_READ(p);                                                              \
    MFMA48(bhA, blA);                                                        \
    DS_READ((p) + 1);                                                        \
    MFMA48(bhB, blB);                                                        \
  } while (0)

  for (int s = 0; s < 8; s += 2) {
    PHASE(2 * s, 0);
    PHASE(2 * s + 2, 2);
  }
  #undef PHASE
  #undef SYNC
  #undef MFMA48
  #undef DS_READ
  #undef CONVERT_STORE
  #undef LOAD_B
  #undef LOAD_A

  // ---- epilogue: bf16 U store + fused 64-row chunk carry ----
  // wave's rows = one chunk (index 2*blockIdx+wm): t = mf*16 + lg*4 + j,
  // weight a^{63-t} = P4^{3-lg} * P16^{3-mf} * a^{3-j}
  #pragma unroll
  for (int nf = 0; nf < 4; ++nf) {
    const int n = wn * 64 + nf * 16 + lr;
    const float bv = bias[n];
    const float ar_ = consts[n],           ai_ = consts[Ksz + n];
    const float p4r = consts[4 * Ksz + n], p4i = consts[5 * Ksz + n];
    const float p8r = consts[6 * Ksz + n], p8i = consts[7 * Ksz + n];
    const float p16r = consts[8 * Ksz + n], p16i = consts[9 * Ksz + n];
    const int e = 3 - lg;
    const float b1r = (e & 1) ? p4r : 1.f, b1i = (e & 1) ? p4i : 0.f;
    const float b2r = (e & 2) ? p8r : 1.f, b2i = (e & 2) ? p8i : 0.f;
    float wr = b1r * b2r - b1i * b2i;
    float wi = b1r * b2i + b1i * b2r;
    float Sr = 0.f, Si = 0.f;
    #pragma unroll
    for (int mf = 3; mf >= 0; --mf) {
      float vr = wr, vi = wi;
      #pragma unroll
      for (int j = 3; j >= 0; --j) {
        const float u = acc[mf][nf][j] + bv;
        U[(m0 + wm * 64 + mf * 16 + lg * 4 + j) * Ksz + n] =
            (unsigned short)bf16rne(u);
        Sr = fmaf(u, vr, Sr);
        Si = fmaf(u, vi, Si);
        if (j) {
          float t_ = vr * ar_ - vi * ai_;
          vi = vr * ai_ + vi * ar_;
          vr = t_;
        }
      }
      if (mf) {
        float t_ = wr * p16r - wi * p16i;
        wi = wr * p16i + wi * p16r;
        wr = t_;
      }
    }
    Sr += __shfl_xor(Sr, 16); Si += __shfl_xor(Si, 16);
    Sr += __shfl_xor(Sr, 32); Si += __shfl_xor(Si, 32);
    if (lg == 0)
      ((float2*)carry)[(size_t)(blockIdx.x * 2 + wm) * Ksz + n] =
          make_float2(Sr, Si);
  }
}

// --------- scan pass 2: exclusive prefix over chunks (A = a^64) ------------
// Software-prefetch: load carry(m+1) before consuming carry(m) to hide the
// ~250cy L2 latency of the 64-step serial chain.
__global__ __launch_bounds__(64) void scan_prefix(
    const float* __restrict__ consts, const float* __restrict__ carry,
    float* __restrict__ prefix) {
  const int k = blockIdx.y * 64 + threadIdx.x;
  const int b = blockIdx.x;
  const float Ar = consts[2 * Ksz + k], Ai = consts[3 * Ksz + k];
  const float2* cp = (const float2*)carry;
  float2* pp = (float2*)prefix;
  const size_t base = (size_t)(b * NCH) * Ksz + k;
  float c = 0.f, s = 0.f;
  float2 L = cp[base];
  for (int m = 0; m < NCH; ++m) {
    float2 Lnext = make_float2(0.f, 0.f);
    if (m + 1 < NCH) Lnext = cp[base + (size_t)(m + 1) * Ksz];
    pp[base + (size_t)m * Ksz] = make_float2(c, s);
    float cn = fmaf(Ar, c, fmaf(-Ai, s, L.x));
    float sn = fmaf(Ai, c, fmaf(Ar, s, L.y));
    c = cn; s = sn;
    L = Lnext;
  }
}

// --------- scan pass 3: rescan chunk from true carry, write output ---------
// 4 k's per thread: u64 U-loads (8B/lane) + float4 stores (16B/lane).
// Per-k math and order identical to prior rounds.
__global__ __launch_bounds__(256) void scan_final(
    const unsigned short* __restrict__ U, const float* __restrict__ consts,
    const float* __restrict__ prefix, float* __restrict__ out) {
  const int tid = threadIdx.x;
  const int bm = blockIdx.x * 4 + (tid >> 6);
  const int k0 = (tid & 63) * 4;
  float ar[4], ai[4], c[4], s[4];
  #pragma unroll
  for (int j = 0; j < 4; ++j) {
    ar[j] = consts[k0 + j];
    ai[j] = consts[Ksz + k0 + j];
    float2 w = ((const float2*)prefix)[(size_t)bm * Ksz + k0 + j];
    c[j] = w.x; s[j] = w.y;
  }
  const unsigned short* up = U + (size_t)bm * (CHUNK * Ksz) + k0;
  float* op = out + (size_t)bm * (CHUNK * 2 * Ksz) + k0;
  for (int t = 0; t < CHUNK; ++t) {
    unsigned long long uv = *(const unsigned long long*)(up + (size_t)t * Ksz);
    #pragma unroll
    for (int j = 0; j < 4; ++j) {
      float u = __uint_as_float(((unsigned int)(uv >> (16 * j))) << 16);
      float cn = fmaf(ar[j], c[j], fmaf(-ai[j], s[j], u));
      s[j] = fmaf(ai[j], c[j], ar[j] * s[j]);
      c[j] = cn;
    }
    *(float4*)(op + (size_t)t * 2 * Ksz) = make_float4(c[0], c[1], c[2], c[3]);
    *(float4*)(op + (size_t)t * 2 * Ksz + Ksz) =
        make_float4(s[0], s[1], s[2], s[3]);
  }
}

extern "C" void kernel_launch(void* const* d_in, const int* in_sizes, int n_in,
                              void* d_out, int out_size, void* d_ws, size_t ws_size,
                              hipStream_t stream) {
  const float* x    = (const float*)d_in[0];
  const float* srr  = (const float*)d_in[1];
  const float* sim  = (const float*)d_in[2];
  const float* traw = (const float*)d_in[3];
  const float* W    = (const float*)d_in[4];
  const float* bias = (const float*)d_in[5];
  float* out = (float*)d_out;

  // ws layout (floats): consts[4096] | U(bf16: Msz*Ksz ushorts = 8388608 fl)
  //   | carry[524288] | prefix[524288] | WfH[65536] | WfL[65536]
  //   | partial_v[8192] | wv[256]
  float* wsf    = (float*)d_ws;
  float* consts = wsf;
  unsigned short* U = (unsigned short*)(wsf + 4096);
  float* carry  = wsf + 4096 + 8388608;
  float* prefix = carry + (size_t)2 * Bsz * NCH * Ksz;
  unsigned int* WfH = (unsigned int*)(prefix + (size_t)2 * Bsz * NCH * Ksz);
  unsigned int* WfL = WfH + 65536;
  float* partial_v  = (float*)(WfL + 65536);
  float* wv         = partial_v + 16 * Dsz;

  prep1_kernel<<<16, 512, 0, stream>>>(W, partial_v);
  prep2_kernel<<<64, 512, 0, stream>>>(W, partial_v, wv);
  prep3_kernel<<<1, 256, 0, stream>>>(srr, sim, traw, wv, consts);
  wpack_kernel<<<256, 64, 0, stream>>>(W, consts, WfH, WfL);
  gemm_mfma<<<Msz / 128, 512, 0, stream>>>(x, WfH, WfL, bias, consts, U, carry);
  scan_prefix<<<dim3(Bsz, Ksz / 64), 64, 0, stream>>>(consts, carry, prefix);
  scan_final<<<Bsz * NCH / 4, 256, 0, stream>>>(U, consts, prefix, out);
}

// Round 16
// 111.683 us; speedup vs baseline: 1.1878x; 1.0083x over previous
//
#include <hip/hip_runtime.h>

#define Bsz 16
#define Tsz 4096
#define Dsz 512
#define Ksz 256
#define Msz (Bsz * Tsz)      // 65536
#define CHUNK 64
#define NCH (Tsz / CHUNK)    // 64

typedef __attribute__((ext_vector_type(8))) short short8;
typedef __attribute__((ext_vector_type(4))) float f32x4;

// ---------------- threefry2x32 (key = (0, 42)) — matches JAX exactly -------
__device__ __forceinline__ unsigned int rotl32(unsigned int x, int d) {
  return (x << d) | (x >> (32 - d));
}

__device__ void threefry_pair(unsigned int c0, unsigned int c1,
                              unsigned int& o0, unsigned int& o1) {
  const unsigned int k0 = 0u, k1 = 42u;
  const unsigned int k2 = k0 ^ k1 ^ 0x1BD11BDAu;
  unsigned int x0 = c0 + k0;
  unsigned int x1 = c1 + k1;
#define TF_ROUND(r) { x0 += x1; x1 = rotl32(x1, (r)); x1 ^= x0; }
  TF_ROUND(13) TF_ROUND(15) TF_ROUND(26) TF_ROUND(6)
  x0 += k1; x1 += k2 + 1u;
  TF_ROUND(17) TF_ROUND(29) TF_ROUND(16) TF_ROUND(24)
  x0 += k2; x1 += k0 + 2u;
  TF_ROUND(13) TF_ROUND(15) TF_ROUND(26) TF_ROUND(6)
  x0 += k0; x1 += k1 + 3u;
  TF_ROUND(17) TF_ROUND(29) TF_ROUND(16) TF_ROUND(24)
  x0 += k1; x1 += k2 + 4u;
  TF_ROUND(13) TF_ROUND(15) TF_ROUND(26) TF_ROUND(6)
  x0 += k2; x1 += k0 + 5u;
#undef TF_ROUND
  o0 = x0; o1 = x1;
}

// XLA ErfInv32 polynomial (math.cc)
__device__ float erfinv32(float x) {
  float w = -log1pf(-x * x);
  float p;
  if (w < 5.f) {
    w -= 2.5f;
    p = 2.81022636e-08f;
    p = fmaf(p, w, 3.43273939e-07f);
    p = fmaf(p, w, -3.5233877e-06f);
    p = fmaf(p, w, -4.39150654e-06f);
    p = fmaf(p, w, 0.00021858087f);
    p = fmaf(p, w, -0.00125372503f);
    p = fmaf(p, w, -0.00417768164f);
    p = fmaf(p, w, 0.246640727f);
    p = fmaf(p, w, 1.50140941f);
  } else {
    w = sqrtf(w) - 3.f;
    p = -0.000200214257f;
    p = fmaf(p, w, 0.000100950558f);
    p = fmaf(p, w, 0.00134934322f);
    p = fmaf(p, w, -0.00367342844f);
    p = fmaf(p, w, 0.00573950773f);
    p = fmaf(p, w, -0.0076224613f);
    p = fmaf(p, w, 0.00943887047f);
    p = fmaf(p, w, 1.00167406f);
    p = fmaf(p, w, 2.83297682f);
  }
  return p * x;
}

// JAX: bits -> uniform[-0.99999994, 1) -> sqrt(2)*erfinv
__device__ float bits_to_normal(unsigned int bits) {
  unsigned int fb = (bits >> 9) | 0x3f800000u;
  float f = __uint_as_float(fb) - 1.0f;   // [0,1)
  const float lo = -0.99999994f;          // nextafter(-1, 0) in f32
  float u = f * 2.0f + lo;                // hi - lo rounds to exactly 2.0f
  u = fmaxf(lo, u);
  return 1.41421356f * erfinv32(u);
}

__device__ float block_sum_512(float v, float* s_red) {
  #pragma unroll
  for (int o = 32; o > 0; o >>= 1) v += __shfl_down(v, o);
  const int lane = threadIdx.x & 63, wid = threadIdx.x >> 6;
  if (lane == 0) s_red[wid] = v;
  __syncthreads();
  float r = 0.f;
  #pragma unroll
  for (int i = 0; i < 8; ++i) r += s_red[i];
  __syncthreads();
  return r;
}

__device__ __forceinline__ unsigned int bf16rne(float f) {
  unsigned int u = __float_as_uint(f);
  return (u + 0x7FFFu + ((u >> 16) & 1u)) >> 16;
}

// split 2 floats -> packed hi-trunc (1 v_perm) + packed lo-RNE (v_cvt_pk,
// RNE == bf16rne; src0 -> low16, src1 -> high16: matches prior packing)
__device__ __forceinline__ void split2(float v0, float v1,
                                       unsigned int& hh, unsigned int& ll) {
  unsigned int u0 = __float_as_uint(v0);
  unsigned int u1 = __float_as_uint(v1);
  hh = __builtin_amdgcn_perm(u1, u0, 0x07060302u);   // [u1.hi16 | u0.hi16]
  float r0 = v0 - __uint_as_float(u0 & 0xFFFF0000u);
  float r1 = v1 - __uint_as_float(u1 & 0xFFFF0000u);
  unsigned int r;
  asm("v_cvt_pk_bf16_f32 %0, %1, %2" : "=v"(r) : "v"(r0), "v"(r1));
  ll = r;
}

// --------- prep1 (16 blocks x 512): partial_v[b][d] = sum_k W[k][d]*u0n[k] --
__global__ __launch_bounds__(512) void prep1_kernel(
    const float* __restrict__ W, float* __restrict__ partial_v) {
  __shared__ float s_u0[Ksz];
  __shared__ float s_red[8];
  const int tid = threadIdx.x;
  if (tid < 128) {
    unsigned int y0, y1;
    threefry_pair((unsigned int)tid, (unsigned int)(tid + 128), y0, y1);
    s_u0[tid] = bits_to_normal(y0);
    s_u0[tid + 128] = bits_to_normal(y1);
  }
  __syncthreads();
  float val = (tid < Ksz) ? s_u0[tid] * s_u0[tid] : 0.f;
  float ss = block_sum_512(val, s_red);
  float inv = 1.f / fmaxf(sqrtf(ss), 1e-7f);

  const int k0 = blockIdx.x * 16;
  float acc = 0.f;
  #pragma unroll
  for (int kk = 0; kk < 16; ++kk)
    acc = fmaf(W[(size_t)(k0 + kk) * Dsz + tid], s_u0[k0 + kk], acc);
  partial_v[blockIdx.x * Dsz + tid] = acc * inv;
}

// --------- prep2 (64 blocks x 512): v = normalize(sum partials); wv rows ---
__global__ __launch_bounds__(512) void prep2_kernel(
    const float* __restrict__ W, const float* __restrict__ partial_v,
    float* __restrict__ wv) {
  __shared__ float s_v[Dsz];
  __shared__ float s_red[8];
  __shared__ float s_p[8];
  const int tid = threadIdx.x;
  float acc = 0.f;
  #pragma unroll
  for (int b = 0; b < 16; ++b) acc += partial_v[b * Dsz + tid];
  float ssv = block_sum_512(acc * acc, s_red);
  float invv = 1.f / fmaxf(sqrtf(ssv), 1e-7f);
  s_v[tid] = acc * invv;
  __syncthreads();

  const int k = blockIdx.x * 4 + (tid >> 7);
  const int sub = tid & 127;
  const float* wr = W + (size_t)k * Dsz;
  float p = 0.f;
  #pragma unroll
  for (int j = sub; j < Dsz; j += 128) p = fmaf(wr[j], s_v[j], p);
  #pragma unroll
  for (int o = 32; o > 0; o >>= 1) p += __shfl_down(p, o);
  const int lane = tid & 63, wid = tid >> 6;
  if (lane == 0) s_p[wid] = p;
  __syncthreads();
  if (tid < 4) wv[blockIdx.x * 4 + tid] = s_p[2 * tid] + s_p[2 * tid + 1];
}

// --------- prep3 (1 block x 256): sigma + all per-k constants --------------
// consts layout (floats): [0]=ar [K]=ai [2K]=A64r [3K]=A64i [4K]=P4r [5K]=P4i
//   [6K]=P8r [7K]=P8i [8K]=P16r [9K]=P16i [10K]=P32r [11K]=P32i [12K]=inv_sigma
__global__ __launch_bounds__(256) void prep3_kernel(
    const float* __restrict__ s_real_raw, const float* __restrict__ s_imag,
    const float* __restrict__ tau_raw, const float* __restrict__ wv,
    float* __restrict__ consts) {
  __shared__ float s_p[4];
  const int tid = threadIdx.x;
  float v = wv[tid];
  float v2 = v * v;
  #pragma unroll
  for (int o = 32; o > 0; o >>= 1) v2 += __shfl_down(v2, o);
  const int lane = tid & 63, wid = tid >> 6;
  if (lane == 0) s_p[wid] = v2;
  __syncthreads();
  float sswv = s_p[0] + s_p[1] + s_p[2] + s_p[3];
  float sigma = sswv / fmaxf(sqrtf(sswv), 1e-7f);
  if (tid == 0) consts[12 * Ksz] = 1.f / sigma;

  float tr = tau_raw[0];
  float tau = fmaxf(tr, 0.f) + log1pf(expf(-fabsf(tr))) + 1e-3f;
  float srr = s_real_raw[tid];
  float sp = fmaxf(srr, 0.f) + log1pf(expf(-fabsf(srr)));
  float alpha0 = (sp + 1e-6f) * tau;
  float omega0 = s_imag[tid] * tau;
  const float dt = 1.f / 4095.f;
  float ad = alpha0 * dt, an = omega0 * dt;
  consts[tid]            = expf(-ad) * cosf(an);
  consts[Ksz + tid]      = expf(-ad) * sinf(an);
  consts[2 * Ksz + tid]  = expf(-ad * 64.f) * cosf(an * 64.f);
  consts[3 * Ksz + tid]  = expf(-ad * 64.f) * sinf(an * 64.f);
  consts[4 * Ksz + tid]  = expf(-ad * 4.f) * cosf(an * 4.f);
  consts[5 * Ksz + tid]  = expf(-ad * 4.f) * sinf(an * 4.f);
  consts[6 * Ksz + tid]  = expf(-ad * 8.f) * cosf(an * 8.f);
  consts[7 * Ksz + tid]  = expf(-ad * 8.f) * sinf(an * 8.f);
  consts[8 * Ksz + tid]  = expf(-ad * 16.f) * cosf(an * 16.f);
  consts[9 * Ksz + tid]  = expf(-ad * 16.f) * sinf(an * 16.f);
  consts[10 * Ksz + tid] = expf(-ad * 32.f) * cosf(an * 32.f);
  consts[11 * Ksz + tid] = expf(-ad * 32.f) * sinf(an * 32.f);
}

// --------- wpack: W/sigma -> bf16 h/l in MFMA B-fragment order -------------
__global__ __launch_bounds__(64) void wpack_kernel(
    const float* __restrict__ W, const float* __restrict__ consts,
    unsigned int* __restrict__ WfH, unsigned int* __restrict__ WfL) {
  const int kb = blockIdx.x >> 4;
  const int nb = blockIdx.x & 15;
  const int lane = threadIdx.x;
  const int lr = lane & 15, lg = lane >> 4;
  const float inv_sigma = consts[12 * Ksz];
  const float* src = W + (size_t)(nb * 16 + lr) * Dsz + kb * 32 + lg * 8;
  float v[8];
  *(float4*)&v[0] = *(const float4*)src;
  *(float4*)&v[4] = *(const float4*)(src + 4);
  unsigned int hh[4], ll[4];
  #pragma unroll
  for (int i = 0; i < 4; ++i)
    split2(v[2 * i] * inv_sigma, v[2 * i + 1] * inv_sigma, hh[i], ll[i]);
  const size_t off = (size_t)blockIdx.x * 256 + lane * 4;   // in uints
  *(int4*)(WfH + off) = *(int4*)hh;
  *(int4*)(WfL + off) = *(int4*)ll;
}

// --------- MFMA GEMM + fused chunk-scan carry ------------------------------
// BM=128 (= 2 scan chunks), BN=256, BK=32. 512 threads = 8 waves (2m x 4n).
// SUPER-PHASE schedule (round-15 best): 2 K-tiles per barrier via 4-buffer
// LDS ring; one lgkm-drain + one s_barrier per super-phase. T5 setprio(1)
// wraps the MFMA clusters (2 staggered blocks/CU give the scheduler role
// diversity to arbitrate). U bit-identical; bf16 U store.
__global__ __launch_bounds__(512, 2) void gemm_mfma(
    const float* __restrict__ X, const unsigned int* __restrict__ WfH,
    const unsigned int* __restrict__ WfL, const float* __restrict__ bias,
    const float* __restrict__ consts, unsigned short* __restrict__ U,
    float* __restrict__ carry) {
  __shared__ unsigned int ldsA[4][4096];   // 4 bufs x 16KB: 128 rows x [h|l]

  const int tid = threadIdx.x;
  const size_t m0 = (size_t)blockIdx.x * 128;

  // A staging: thread -> (row sr = tid>>2, k-chunk sc = (tid&3)*8 floats)
  const int sr = tid >> 2;              // 0..127
  const int sc = (tid & 3) * 8;
  const float* gx = X + (m0 + sr) * Dsz + sc;
  const int swz = (sr & 7) << 4;
  const int aoff_h = sr * 128 + ((sc * 2) ^ swz);
  const int aoff_l = sr * 128 + ((64 + sc * 2) ^ swz);

  const int lane = tid & 63;
  const int wid = tid >> 6;             // 0..7
  const int wm = wid >> 2;              // 0..1 -> rows wm*64
  const int wn = wid & 3;               // 0..3 -> cols wn*64
  const int lr = lane & 15;
  const int lg = lane >> 4;

  float xaA[8], xaB[8];
  #define LOAD_A(dst, kb) do {                             \
    const float* p = gx + (kb) * 32;                       \
    *(float4*)&dst[0] = *(const float4*)p;                 \
    *(float4*)&dst[4] = *(const float4*)(p + 4);           \
  } while (0)

  const char* const wfh = (const char*)WfH + (size_t)wn * 4096 + lane * 16;
  const char* const wfl = (const char*)WfL + (size_t)wn * 4096 + lane * 16;

  short8 bhA[4], blA[4], bhB[4], blB[4];
  #define LOAD_B(bh_, bl_, kb) do {                                          \
    const size_t tb = (size_t)(kb) * 16384;                                  \
    _Pragma("unroll")                                                        \
    for (int f = 0; f < 4; ++f) {                                            \
      bh_[f] = *(const short8*)(wfh + tb + (size_t)f * 1024);                \
      bl_[f] = *(const short8*)(wfl + tb + (size_t)f * 1024);                \
    }                                                                        \
  } while (0)

  #define CONVERT_STORE(xa, buf) do {                                        \
    char* const Ab_ = (char*)ldsA[(buf)];                                    \
    unsigned int hh[4], llw[4];                                              \
    _Pragma("unroll")                                                        \
    for (int i = 0; i < 4; ++i)                                              \
      split2(xa[2 * i], xa[2 * i + 1], hh[i], llw[i]);                       \
    *(int4*)(Ab_ + aoff_h) = *(int4*)hh;                                     \
    *(int4*)(Ab_ + aoff_l) = *(int4*)llw;                                    \
  } while (0)

  short8 ah[4], al[4];
  #define DS_READ(buf) do {                                                  \
    const char* const Ab_ = (const char*)ldsA[(buf)];                        \
    _Pragma("unroll")                                                        \
    for (int f = 0; f < 4; ++f) {                                            \
      const int r = wm * 64 + f * 16 + lr;                                   \
      const int sz = (r & 7) << 4;                                           \
      ah[f] = *(const short8*)(Ab_ + r * 128 + ((lg * 16) ^ sz));            \
      al[f] = *(const short8*)(Ab_ + r * 128 + ((64 + lg * 16) ^ sz));       \
    }                                                                        \
  } while (0)

  f32x4 acc[4][4];
  #pragma unroll
  for (int i = 0; i < 4; ++i)
    #pragma unroll
    for (int j = 0; j < 4; ++j) acc[i][j] = (f32x4)(0.f);

  #define MFMA48(bh_, bl_) do {                                              \
    _Pragma("unroll")                                                        \
    for (int mf = 0; mf < 4; ++mf)                                           \
      _Pragma("unroll")                                                      \
      for (int nf = 0; nf < 4; ++nf)                                         \
        acc[mf][nf] = __builtin_amdgcn_mfma_f32_16x16x32_bf16(               \
            ah[mf], bh_[nf], acc[mf][nf], 0, 0, 0);                          \
    _Pragma("unroll")                                                        \
    for (int mf = 0; mf < 4; ++mf)                                           \
      _Pragma("unroll")                                                      \
      for (int nf = 0; nf < 4; ++nf)                                         \
        acc[mf][nf] = __builtin_amdgcn_mfma_f32_16x16x32_bf16(               \
            ah[mf], bl_[nf], acc[mf][nf], 0, 0, 0);                          \
    _Pragma("unroll")                                                        \
    for (int mf = 0; mf < 4; ++mf)                                           \
      _Pragma("unroll")                                                      \
      for (int nf = 0; nf < 4; ++nf)                                         \
        acc[mf][nf] = __builtin_amdgcn_mfma_f32_16x16x32_bf16(               \
            al[mf], bh_[nf], acc[mf][nf], 0, 0, 0);                          \
  } while (0)

  #define SYNC() do {                                                        \
    asm volatile("s_waitcnt lgkmcnt(0)" ::: "memory");                       \
    __builtin_amdgcn_s_barrier();                                            \
    __builtin_amdgcn_sched_barrier(0);                                       \
  } while (0)

  // prologue: raw A for tiles 0,1
  LOAD_A(xaA, 0);
  LOAD_A(xaB, 1);

  // SUPER-PHASE s (k0 = 2s, buffer pair p = (s&1)*2):
  //   issue B(k0), B(k0+1); convert+write pair; prefetch A(k0+2),A(k0+3);
  //   ONE drain+barrier; read+MFMA both tiles (setprio-wrapped).
  #define PHASE(k0, p) do {                                                  \
    LOAD_B(bhA, blA, (k0));                                                  \
    LOAD_B(bhB, blB, (k0) + 1);                                              \
    CONVERT_STORE(xaA, (p));                                                 \
    if ((k0) + 2 < 16) LOAD_A(xaA, (k0) + 2);                                \
    CONVERT_STORE(xaB, (p) + 1);                                             \
    if ((k0) + 3 < 16) LOAD_A(xaB, (k0) + 3);                                \
    SYNC();                                                                  \
    DS_READ(p);                                                              \
    __builtin_amdgcn_s_setprio(1);                                           \
    MFMA48(bhA, blA);                                                        \
    __builtin_amdgcn_s_setprio(0);                                           \
    DS_READ((p) + 1);                                                        \
    __builtin_amdgcn_s_setprio(1);                                           \
    MFMA48(bhB, blB);                                                        \
    __builtin_amdgcn_s_setprio(0);                                           \
  } while (0)

  for (int s = 0; s < 8; s += 2) {
    PHASE(2 * s, 0);
    PHASE(2 * s + 2, 2);
  }
  #undef PHASE
  #undef SYNC
  #undef MFMA48
  #undef DS_READ
  #undef CONVERT_STORE
  #undef LOAD_B
  #undef LOAD_A

  // ---- epilogue: bf16 U store + fused 64-row chunk carry ----
  // wave's rows = one chunk (index 2*blockIdx+wm): t = mf*16 + lg*4 + j,
  // weight a^{63-t} = P4^{3-lg} * P16^{3-mf} * a^{3-j}
  #pragma unroll
  for (int nf = 0; nf < 4; ++nf) {
    const int n = wn * 64 + nf * 16 + lr;
    const float bv = bias[n];
    const float ar_ = consts[n],           ai_ = consts[Ksz + n];
    const float p4r = consts[4 * Ksz + n], p4i = consts[5 * Ksz + n];
    const float p8r = consts[6 * Ksz + n], p8i = consts[7 * Ksz + n];
    const float p16r = consts[8 * Ksz + n], p16i = consts[9 * Ksz + n];
    const int e = 3 - lg;
    const float b1r = (e & 1) ? p4r : 1.f, b1i = (e & 1) ? p4i : 0.f;
    const float b2r = (e & 2) ? p8r : 1.f, b2i = (e & 2) ? p8i : 0.f;
    float wr = b1r * b2r - b1i * b2i;
    float wi = b1r * b2i + b1i * b2r;
    float Sr = 0.f, Si = 0.f;
    #pragma unroll
    for (int mf = 3; mf >= 0; --mf) {
      float vr = wr, vi = wi;
      #pragma unroll
      for (int j = 3; j >= 0; --j) {
        const float u = acc[mf][nf][j] + bv;
        U[(m0 + wm * 64 + mf * 16 + lg * 4 + j) * Ksz + n] =
            (unsigned short)bf16rne(u);
        Sr = fmaf(u, vr, Sr);
        Si = fmaf(u, vi, Si);
        if (j) {
          float t_ = vr * ar_ - vi * ai_;
          vi = vr * ai_ + vi * ar_;
          vr = t_;
        }
      }
      if (mf) {
        float t_ = wr * p16r - wi * p16i;
        wi = wr * p16i + wi * p16r;
        wr = t_;
      }
    }
    Sr += __shfl_xor(Sr, 16); Si += __shfl_xor(Si, 16);
    Sr += __shfl_xor(Sr, 32); Si += __shfl_xor(Si, 32);
    if (lg == 0)
      ((float2*)carry)[(size_t)(blockIdx.x * 2 + wm) * Ksz + n] =
          make_float2(Sr, Si);
  }
}

// --------- scan pass 2: exclusive prefix over chunks (A = a^64) ------------
// Software-prefetch: load carry(m+1) before consuming carry(m).
__global__ __launch_bounds__(64) void scan_prefix(
    const float* __restrict__ consts, const float* __restrict__ carry,
    float* __restrict__ prefix) {
  const int k = blockIdx.y * 64 + threadIdx.x;
  const int b = blockIdx.x;
  const float Ar = consts[2 * Ksz + k], Ai = consts[3 * Ksz + k];
  const float2* cp = (const float2*)carry;
  float2* pp = (float2*)prefix;
  const size_t base = (size_t)(b * NCH) * Ksz + k;
  float c = 0.f, s = 0.f;
  float2 L = cp[base];
  for (int m = 0; m < NCH; ++m) {
    float2 Lnext = make_float2(0.f, 0.f);
    if (m + 1 < NCH) Lnext = cp[base + (size_t)(m + 1) * Ksz];
    pp[base + (size_t)m * Ksz] = make_float2(c, s);
    float cn = fmaf(Ar, c, fmaf(-Ai, s, L.x));
    float sn = fmaf(Ai, c, fmaf(Ar, s, L.y));
    c = cn; s = sn;
    L = Lnext;
  }
}

// --------- scan pass 3: rescan chunk from true carry, write output ---------
// 4 k's per thread: u64 U-loads (8B/lane) + float4 stores (16B/lane).
__global__ __launch_bounds__(256) void scan_final(
    const unsigned short* __restrict__ U, const float* __restrict__ consts,
    const float* __restrict__ prefix, float* __restrict__ out) {
  const int tid = threadIdx.x;
  const int bm = blockIdx.x * 4 + (tid >> 6);
  const int k0 = (tid & 63) * 4;
  float ar[4], ai[4], c[4], s[4];
  #pragma unroll
  for (int j = 0; j < 4; ++j) {
    ar[j] = consts[k0 + j];
    ai[j] = consts[Ksz + k0 + j];
    float2 w = ((const float2*)prefix)[(size_t)bm * Ksz + k0 + j];
    c[j] = w.x; s[j] = w.y;
  }
  const unsigned short* up = U + (size_t)bm * (CHUNK * Ksz) + k0;
  float* op = out + (size_t)bm * (CHUNK * 2 * Ksz) + k0;
  for (int t = 0; t < CHUNK; ++t) {
    unsigned long long uv = *(const unsigned long long*)(up + (size_t)t * Ksz);
    #pragma unroll
    for (int j = 0; j < 4; ++j) {
      float u = __uint_as_float(((unsigned int)(uv >> (16 * j))) << 16);
      float cn = fmaf(ar[j], c[j], fmaf(-ai[j], s[j], u));
      s[j] = fmaf(ai[j], c[j], ar[j] * s[j]);
      c[j] = cn;
    }
    *(float4*)(op + (size_t)t * 2 * Ksz) = make_float4(c[0], c[1], c[2], c[3]);
    *(float4*)(op + (size_t)t * 2 * Ksz + Ksz) =
        make_float4(s[0], s[1], s[2], s[3]);
  }
}

extern "C" void kernel_launch(void* const* d_in, const int* in_sizes, int n_in,
                              void* d_out, int out_size, void* d_ws, size_t ws_size,
                              hipStream_t stream) {
  const float* x    = (const float*)d_in[0];
  const float* srr  = (const float*)d_in[1];
  const float* sim  = (const float*)d_in[2];
  const float* traw = (const float*)d_in[3];
  const float* W    = (const float*)d_in[4];
  const float* bias = (const float*)d_in[5];
  float* out = (float*)d_out;

  // ws layout (floats): consts[4096] | U(bf16: Msz*Ksz ushorts = 8388608 fl)
  //   | carry[524288] | prefix[524288] | WfH[65536] | WfL[65536]
  //   | partial_v[8192] | wv[256]
  float* wsf    = (float*)d_ws;
  float* consts = wsf;
  unsigned short* U = (unsigned short*)(wsf + 4096);
  float* carry  = wsf + 4096 + 8388608;
  float* prefix = carry + (size_t)2 * Bsz * NCH * Ksz;
  unsigned int* WfH = (unsigned int*)(prefix + (size_t)2 * Bsz * NCH * Ksz);
  unsigned int* WfL = WfH + 65536;
  float* partial_v  = (float*)(WfL + 65536);
  float* wv         = partial_v + 16 * Dsz;

  prep1_kernel<<<16, 512, 0, stream>>>(W, partial_v);
  prep2_kernel<<<64, 512, 0, stream>>>(W, partial_v, wv);
  prep3_kernel<<<1, 256, 0, stream>>>(srr, sim, traw, wv, consts);
  wpack_kernel<<<256, 64, 0, stream>>>(W, consts, WfH, WfL);
  gemm_mfma<<<Msz / 128, 512, 0, stream>>>(x, WfH, WfL, bias, consts, U, carry);
  scan_prefix<<<dim3(Bsz, Ksz / 64), 64, 0, stream>>>(consts, carry, prefix);
  scan_final<<<Bsz * NCH / 4, 256, 0, stream>>>(U, consts, prefix, out);
}